// Round 4
// baseline (911.000 us; speedup 1.0000x reference)
//
#include <hip/hip_runtime.h>
#include <hip/hip_bf16.h>

// ---------------- common helpers ----------------
typedef unsigned short u16;
typedef __attribute__((ext_vector_type(8))) short bf16x8;
typedef __attribute__((ext_vector_type(4))) float floatx4;

__device__ __forceinline__ u16 f2b(float f) {
    union { float f; unsigned int u; } a; a.f = f;
    unsigned int u = a.u;
    unsigned int r = (u + 0x7fffu + ((u >> 16) & 1u)) >> 16; // RNE bf16
    return (u16)r;
}
__device__ __forceinline__ float b2f(u16 v) {
    union { unsigned int u; float f; } a; a.u = ((unsigned int)v) << 16;
    return a.f;
}
// pack two f32 -> one u32 of 2x bf16 (RNE), single instruction
__device__ __forceinline__ unsigned int cvt_pk_bf16(float lo, float hi) {
    unsigned int r;
    asm("v_cvt_pk_bf16_f32 %0, %1, %2" : "=v"(r) : "v"(lo), "v"(hi));
    return r;
}

// async global->LDS, 16B per lane (global_load_lds_dwordx4)
__device__ __forceinline__ void gload_lds16(const void* g, void* l) {
    auto gp = (const __attribute__((address_space(1))) unsigned int*)g;
    auto lp = (__attribute__((address_space(3))) unsigned int*)l;
    __builtin_amdgcn_global_load_lds(gp, lp, 16, 0, 0);
}

// pinned raw barrier (schedule may not cross)
__device__ __forceinline__ void sbar() {
    __builtin_amdgcn_sched_barrier(0);
    __builtin_amdgcn_s_barrier();
    __builtin_amdgcn_sched_barrier(0);
}

// ---------------- LayerNorm (ddof=1), bf16 out ----------------
__global__ __launch_bounds__(256) void k_ln_bf(const float* __restrict__ x,
                                               const float* __restrict__ g,
                                               const float* __restrict__ be,
                                               u16* __restrict__ yb) {
    const int row = blockIdx.x;
    const int t = threadIdx.x;
    const float4 xv = ((const float4*)(x + (size_t)row * 1024))[t];
    float s  = xv.x + xv.y + xv.z + xv.w;
    float ss = xv.x * xv.x + xv.y * xv.y + xv.z * xv.z + xv.w * xv.w;
    for (int m = 1; m < 64; m <<= 1) {
        s  += __shfl_xor(s, m);
        ss += __shfl_xor(ss, m);
    }
    __shared__ float sm[8];
    const int wave = t >> 6, lane = t & 63;
    if (lane == 0) { sm[wave] = s; sm[4 + wave] = ss; }
    __syncthreads();
    s  = sm[0] + sm[1] + sm[2] + sm[3];
    ss = sm[4] + sm[5] + sm[6] + sm[7];
    const float mean = s * (1.0f / 1024.0f);
    const float var  = (ss - 1024.0f * mean * mean) * (1.0f / 1023.0f); // ddof=1
    const float rstd = rsqrtf(var + 1e-5f);
    const float4 gv = ((const float4*)g)[t];
    const float4 bv = ((const float4*)be)[t];
    float4 y;
    y.x = (xv.x - mean) * rstd * gv.x + bv.x;
    y.y = (xv.y - mean) * rstd * gv.y + bv.y;
    y.z = (xv.z - mean) * rstd * gv.z + bv.z;
    y.w = (xv.w - mean) * rstd * gv.w + bv.w;
    uint2 pk;
    pk.x = (unsigned int)f2b(y.x) | ((unsigned int)f2b(y.y) << 16);
    pk.y = (unsigned int)f2b(y.z) | ((unsigned int)f2b(y.w) << 16);
    *(uint2*)(yb + (size_t)row * 1024 + t * 4) = pk;
}

// ---------------- weight transpose + convert: W(KxN) fp32 -> Wt(NxK) bf16 ----------------
__global__ __launch_bounds__(256) void k_tconv(const float* __restrict__ W,
                                               u16* __restrict__ Wt,
                                               int K, int N) {
    __shared__ float tile[32][33];
    const int n0 = blockIdx.x * 32, k0 = blockIdx.y * 32;
    const int tx = threadIdx.x, ty = threadIdx.y; // 32 x 8
    for (int i = 0; i < 4; i++) {
        const int kr = ty + i * 8;
        tile[kr][tx] = W[(size_t)(k0 + kr) * N + n0 + tx];
    }
    __syncthreads();
    for (int i = 0; i < 4; i++) {
        const int nr = ty + i * 8;
        Wt[(size_t)(n0 + nr) * K + k0 + tx] = f2b(tile[tx][nr]);
    }
}

// batched version for the four 1024x1024 weights (z selects)
__global__ __launch_bounds__(256) void k_tconv4(const float* __restrict__ s0, u16* __restrict__ d0,
                                                const float* __restrict__ s1, u16* __restrict__ d1,
                                                const float* __restrict__ s2, u16* __restrict__ d2,
                                                const float* __restrict__ s3, u16* __restrict__ d3) {
    __shared__ float tile[32][33];
    const float* W; u16* Wt;
    switch (blockIdx.z) {
        case 0: W = s0; Wt = d0; break;
        case 1: W = s1; Wt = d1; break;
        case 2: W = s2; Wt = d2; break;
        default: W = s3; Wt = d3; break;
    }
    const int n0 = blockIdx.x * 32, k0 = blockIdx.y * 32;
    const int tx = threadIdx.x, ty = threadIdx.y;
    for (int i = 0; i < 4; i++) {
        const int kr = ty + i * 8;
        tile[kr][tx] = W[(size_t)(k0 + kr) * 1024 + n0 + tx];
    }
    __syncthreads();
    for (int i = 0; i < 4; i++) {
        const int nr = ty + i * 8;
        Wt[(size_t)(n0 + nr) * 1024 + k0 + tx] = f2b(tile[tx][nr]);
    }
}

// ---------------- per-head V transpose: v[b*T][D] -> vt[b][h][d][t] (bf16) ----------------
__global__ __launch_bounds__(256) void k_vtrans(const u16* __restrict__ v,
                                                u16* __restrict__ vt) {
    __shared__ u16 tile[64][80];
    const int t = threadIdx.x;
    const int t0 = blockIdx.x * 64, hh = blockIdx.y, bb = blockIdx.z;
    const int r = t >> 2, c0 = (t & 3) * 16;
    const u16* src = v + ((size_t)(bb * 1024 + t0 + r)) * 1024 + hh * 64 + c0;
    *(uint4*)&tile[r][c0]     = *(const uint4*)src;
    *(uint4*)&tile[r][c0 + 8] = *(const uint4*)(src + 8);
    __syncthreads();
    const int d = t >> 2;
    u16* dst = vt + (((size_t)(bb * 16 + hh) * 64 + d)) * 1024 + t0 + c0;
    union { u16 s[8]; uint4 v4; } pk;
    for (int j = 0; j < 8; j++) pk.s[j] = tile[c0 + j][d];
    *(uint4*)dst = pk.v4;
    for (int j = 0; j < 8; j++) pk.s[j] = tile[c0 + 8 + j][d];
    *(uint4*)(dst + 8) = pk.v4;
}

// ---------------- 128x128 bf16 MFMA GEMM (kept for Wo / FFN2) ----------------
template <bool GELU, bool RESID, bool WF32, bool WBF16, bool QKV = false>
__global__ __launch_bounds__(256) void k_gemm(const u16* __restrict__ A,
                                              const u16* __restrict__ Bt,
                                              const float* __restrict__ bias,
                                              const u16* __restrict__ residB,
                                              float* __restrict__ outF,
                                              u16* __restrict__ outB,
                                              int M, int N, int K,
                                              const float* __restrict__ bias2 = nullptr,
                                              const float* __restrict__ bias3 = nullptr) {
    __shared__ __align__(16) u16 S[16896]; // As(8192) | Bs(8192); epilogue: 128x132 ctile
    u16* As = S;
    u16* Bs = S + 8192;
    const int t = threadIdx.x;

    // group-m swizzle
    const int nb = gridDim.x;
    const int linear = blockIdx.y * nb + blockIdx.x;
    const int per = nb * 8;
    const int gg = linear / per, rr = linear % per;
    const int m0 = (gg * 8 + (rr & 7)) * 128;
    const int n0 = (rr >> 3) * 128;

    const int lane = t & 63, wave = t >> 6;
    const int wm = (wave >> 1) * 64, wn = (wave & 1) * 64;
    const int r16 = lane & 15, quad = lane >> 4;

    floatx4 acc[4][4];
    const floatx4 zero = {0.0f, 0.0f, 0.0f, 0.0f};
    for (int i = 0; i < 4; i++)
        for (int j = 0; j < 4; j++) acc[i][j] = zero;

    const u16* pa[4];
    const u16* pb[4];
    #pragma unroll
    for (int i = 0; i < 4; i++) {
        const int L = t + i * 256;
        const int row = L >> 3, col = L & 7;
        const int gcol = col ^ (row & 7);
        pa[i] = A  + (size_t)(m0 + row) * K + gcol * 8;
        pb[i] = Bt + (size_t)(n0 + row) * K + gcol * 8;
    }

    for (int kk = 0; kk < K; kk += 64) {
        #pragma unroll
        for (int i = 0; i < 4; i++) {
            gload_lds16(pa[i] + kk, As + (t + i * 256) * 8);
            gload_lds16(pb[i] + kk, Bs + (t + i * 256) * 8);
        }
        __syncthreads();

        #pragma unroll
        for (int ks = 0; ks < 2; ks++) {
            bf16x8 af[4], bfr[4];
            #pragma unroll
            for (int i = 0; i < 4; i++) {
                const int ra = wm + i * 16 + r16;
                af[i] = *(const bf16x8*)(As + ra * 64 + (((ks << 2) + quad) ^ (ra & 7)) * 8);
                const int rb = wn + i * 16 + r16;
                bfr[i] = *(const bf16x8*)(Bs + rb * 64 + (((ks << 2) + quad) ^ (rb & 7)) * 8);
            }
            #pragma unroll
            for (int mi = 0; mi < 4; mi++)
                #pragma unroll
                for (int ni = 0; ni < 4; ni++)
                    acc[mi][ni] = __builtin_amdgcn_mfma_f32_16x16x32_bf16(af[mi], bfr[ni], acc[mi][ni], 0, 0, 0);
        }
        __syncthreads();
    }

    const int sect = QKV ? (n0 >> 10) : 0;
    const float* bp = QKV ? (sect == 0 ? bias : (sect == 1 ? bias2 : bias3)) : bias;
    u16* outQ = QKV ? (outB + (size_t)sect * (8192ull * 1024ull)) : outB;

    if (WBF16) {
        u16 (*ct)[132] = (u16(*)[132])S;
        for (int mi = 0; mi < 4; mi++)
            for (int ni = 0; ni < 4; ni++) {
                const int col = wn + ni * 16 + r16;
                const int coln = QKV ? ((n0 + col) & 1023) : (n0 + col);
                const float bv = bp[coln];
                for (int r = 0; r < 4; r++) {
                    const int row = wm + mi * 16 + quad * 4 + r;
                    float v = acc[mi][ni][r] + bv;
                    if (GELU) v = 0.5f * v * (1.0f + erff(v * 0.70710678118654752f));
                    ct[row][col] = f2b(v);
                }
            }
        __syncthreads();
        const int orow = t >> 1, oc = (t & 1) * 64;
        const int grow = m0 + orow;
        u16* dst = QKV ? (outQ + (size_t)grow * 1024 + ((n0 + oc) & 1023))
                       : (outB + (size_t)grow * N + n0 + oc);
        #pragma unroll
        for (int j = 0; j < 8; j++)
            *(uint4*)(dst + j * 8) = *(const uint4*)&ct[orow][oc + j * 8];
    } else {
        for (int mi = 0; mi < 4; mi++)
            for (int ni = 0; ni < 4; ni++) {
                const int gcol = n0 + wn + ni * 16 + r16;
                const float bv = bias[gcol];
                for (int r = 0; r < 4; r++) {
                    const int grow = m0 + wm + mi * 16 + quad * 4 + r;
                    float v = acc[mi][ni][r] + bv;
                    if (GELU) v = 0.5f * v * (1.0f + erff(v * 0.70710678118654752f));
                    const size_t o = (size_t)grow * N + gcol;
                    if (RESID) v += b2f(residB[o]);
                    if (WF32) outF[o] = v;
                }
            }
    }
}

// ---------------- 256x256 8-phase bf16 MFMA GEMM (T2+T3+T4+T5) ----------------
// 512 threads = 8 waves (2M x 4N), per-wave output 128x64, BK=64.
// __launch_bounds__(512, 2): 2 waves/SIMD = 1 block/CU (LDS forces this anyway)
// -> 256-VGPR budget, no scratch spill (round-3 lesson: default budget was 128
// and the 128-VGPR accumulator spilled -> 551MB scratch writes).
// Ring-phase fragment schedule: per phase only av[2][4](32) + bv[2][2](16)
// live next to acc(128); quadrant order Q00->Q10->Q11->Q01 shares one operand
// half between consecutive phases.
// Counted vmcnt(8): one K-tile of loads stays in flight across barriers.
template <bool GELU, bool QKV>
__global__ __launch_bounds__(512, 2) void k_gemm256(const u16* __restrict__ A,
                                                    const u16* __restrict__ Bt,
                                                    const float* __restrict__ bias,
                                                    u16* __restrict__ outB,
                                                    int M, int N, int K,
                                                    const float* __restrict__ bias2 = nullptr,
                                                    const float* __restrict__ bias3 = nullptr) {
    __shared__ __align__(16) u16 S[65536]; // 128 KB
    const int t = threadIdx.x;
    const int lane = t & 63, wave = t >> 6;
    const int wm = wave >> 2, wn = wave & 3;          // 2 x 4 wave grid
    const int r16 = lane & 15, quad = lane >> 4;

    // group-m swizzle (8 m-tiles per group span all n-tiles)
    const int nb = gridDim.x;
    const int linear = blockIdx.y * nb + blockIdx.x;
    const int per = nb * 8;
    const int gg = linear / per, rr = linear % per;
    const int m0 = (gg * 8 + (rr & 7)) * 256;
    const int n0 = (rr >> 3) * 256;

    floatx4 acc[8][4];
    const floatx4 zero = {0.0f, 0.0f, 0.0f, 0.0f};
    #pragma unroll
    for (int i = 0; i < 8; i++)
        #pragma unroll
        for (int j = 0; j < 4; j++) acc[i][j] = zero;

    // staging chunk offsets: chunk L=(row,col), source col pre-swizzled:
    // gcol = col ^ (row & 7). LDS[row][col] = G[row][col^(row&7)].
    int offA[4], offB[4];
    #pragma unroll
    for (int i = 0; i < 4; i++) {
        const int L = t + i * 512;
        const int row = L >> 3, col = L & 7;
        const int gcol = col ^ (row & 7);
        offA[i] = (m0 + row) * K + gcol * 8;
        offB[i] = (n0 + row) * K + gcol * 8;
    }

    auto stage = [&](int buf, int kk) {
        #pragma unroll
        for (int i = 0; i < 4; i++) {
            gload_lds16(A + offA[i] + kk, S + buf * 32768 + (t + i * 512) * 8);
            gload_lds16(Bt + offB[i] + kk, S + 16384 + buf * 32768 + (t + i * 512) * 8);
        }
    };

    const int NT = K >> 6;
    stage(0, 0);
    stage(1, 64);
    asm volatile("s_waitcnt vmcnt(8)" ::: "memory"); // buf0 ready, buf1 in flight
    sbar();

    for (int kt = 0; kt < NT; kt++) {
        const int cur = kt & 1;
        const u16* As = S + cur * 32768;
        const u16* Bs = S + 16384 + cur * 32768;

        bf16x8 av[2][4], bv[2][2];

        auto readA = [&](int half) {
            #pragma unroll
            for (int ks = 0; ks < 2; ks++)
                #pragma unroll
                for (int mi = 0; mi < 4; mi++) {
                    const int ra = wm * 128 + half + mi * 16 + r16;
                    av[ks][mi] = *(const bf16x8*)(As + ra * 64 + (((ks << 2) + quad) ^ (ra & 7)) * 8);
                }
        };
        auto readB = [&](int half) {
            #pragma unroll
            for (int ks = 0; ks < 2; ks++)
                #pragma unroll
                for (int ni = 0; ni < 2; ni++) {
                    const int rb = wn * 64 + half + ni * 16 + r16;
                    bv[ks][ni] = *(const bf16x8*)(Bs + rb * 64 + (((ks << 2) + quad) ^ (rb & 7)) * 8);
                }
        };
        auto quadmm = [&](int mo, int no) {
            __builtin_amdgcn_s_setprio(1);
            #pragma unroll
            for (int ks = 0; ks < 2; ks++)
                #pragma unroll
                for (int mi = 0; mi < 4; mi++)
                    #pragma unroll
                    for (int ni = 0; ni < 2; ni++)
                        acc[mo + mi][no + ni] = __builtin_amdgcn_mfma_f32_16x16x32_bf16(
                            av[ks][mi], bv[ks][ni], acc[mo + mi][no + ni], 0, 0, 0);
            __builtin_amdgcn_s_setprio(0);
        };

        // phase 0: Q00 — read a-lo, b-lo
        readA(0); readB(0);
        sbar();
        quadmm(0, 0);
        // phase 1: Q10 — read a-hi (b-lo still live)
        readA(64);
        sbar();
        quadmm(4, 0);
        // phase 2: Q11 — read b-hi (a-hi still live)
        readB(32);
        sbar();
        quadmm(4, 2);
        // phase 3: Q01 — re-read a-lo (b-hi still live)
        readA(0);
        sbar();
        quadmm(0, 2);

        // boundary: all reads of buf[cur] done -> restage it for kt+2
        sbar();
        if (kt + 2 < NT) {
            stage(cur, (kt + 2) << 6);
            asm volatile("s_waitcnt vmcnt(8)" ::: "memory"); // kt+1's 8 loads done
        } else if (kt + 1 < NT) {
            asm volatile("s_waitcnt vmcnt(0)" ::: "memory");
        }
        sbar();
    }

    // ---- epilogue: bias(+GELU) -> LDS repack -> coalesced 16B stores
    const int sect = QKV ? (n0 >> 10) : 0;
    const float* bp = QKV ? (sect == 0 ? bias : (sect == 1 ? bias2 : bias3)) : bias;
    u16* outQ = QKV ? (outB + (size_t)sect * (8192ull * 1024ull)) : outB;

    float bvv[4];
    #pragma unroll
    for (int ni = 0; ni < 4; ni++) {
        const int col = wn * 64 + ni * 16 + r16;
        bvv[ni] = bp[QKV ? ((n0 + col) & 1023) : (n0 + col)];
    }
    u16 (*ct)[260] = (u16(*)[260])S; // 128 x 260 u16 = 66.5 KB
    __syncthreads();
    for (int mh = 0; mh < 2; mh++) {
        if (wm == mh) {
            #pragma unroll
            for (int mi = 0; mi < 8; mi++)
                #pragma unroll
                for (int ni = 0; ni < 4; ni++) {
                    const int col = wn * 64 + ni * 16 + r16;
                    #pragma unroll
                    for (int r = 0; r < 4; r++) {
                        float v = acc[mi][ni][r] + bvv[ni];
                        if (GELU) v = 0.5f * v * (1.0f + erff(v * 0.70710678118654752f));
                        ct[mi * 16 + quad * 4 + r][col] = f2b(v);
                    }
                }
        }
        __syncthreads();
        const int orow = t >> 2, oc = (t & 3) * 64;
        const int grow = m0 + mh * 128 + orow;
        u16* dst = QKV ? (outQ + (size_t)grow * 1024 + ((n0 + oc) & 1023))
                       : (outB + (size_t)grow * N + n0 + oc);
        #pragma unroll
        for (int j = 0; j < 8; j++)
            *(uint4*)(dst + j * 8) = *(const uint4*)&ct[orow][oc + j * 8];
        __syncthreads();
    }
}

// ---------------- bf16 MFMA flash attention (v3, swapped QK^T softmax) ----------------
__global__ __launch_bounds__(256) void k_attn_mfma(const u16* __restrict__ q,
                                                   const u16* __restrict__ k,
                                                   const u16* __restrict__ vt,
                                                   u16* __restrict__ ctx) {
    __shared__ u16 Ks[2][64][40];
    __shared__ u16 Vs[2][64][40];
    __shared__ u16 Ps[2][64][40];
    const int t = threadIdx.x;
    const int lane = t & 63, wave = t >> 6;
    const int r16 = lane & 15, quad = lane >> 4;
    const int wq = wave * 16;
    const int bx = blockIdx.x;
    const int qt = bx & 15, hh = (bx >> 4) & 15, bb = bx >> 8;
    const size_t qk_base = ((size_t)bb * 1024) * 1024 + hh * 64;
    const size_t vt_base = ((size_t)(bb * 16 + hh) * 64) * 1024;
    const int q0 = qt * 64;
    const float C1 = 0.18033688011112042f; // 0.125 * log2(e)

    bf16x8 qf[2];
    {
        const u16* qp = q + qk_base + (size_t)(q0 + wq + r16) * 1024 + quad * 8;
        qf[0] = *(const bf16x8*)qp;
        qf[1] = *(const bf16x8*)(qp + 32);
    }

    const int srow = t >> 2, ch = t & 3;
    const int pnl = ch >> 1, soff = (ch & 1) * 16;
    const u16* gkb = k + qk_base + (size_t)srow * 1024 + ch * 16;
    const u16* gvb = vt + vt_base + (size_t)srow * 1024 + ch * 16;

    uint4 k0v = *(const uint4*)gkb;
    uint4 k1v = *(const uint4*)(gkb + 8);
    uint4 v0v = *(const uint4*)gvb;
    uint4 v1v = *(const uint4*)(gvb + 8);

    float m_i = -INFINITY, l_i = 0.0f;
    floatx4 acc_o[4];
    const floatx4 zero = {0.0f, 0.0f, 0.0f, 0.0f};
    for (int ni = 0; ni < 4; ni++) acc_o[ni] = zero;

    for (int st = 0; st < 16; st++) {
        *(uint4*)&Ks[pnl][srow][soff]     = k0v;
        *(uint4*)&Ks[pnl][srow][soff + 8] = k1v;
        *(uint4*)&Vs[pnl][srow][soff]     = v0v;
        *(uint4*)&Vs[pnl][srow][soff + 8] = v1v;
        __syncthreads();

        const int sn = (st + 1) & 15;
        const u16* gk = gkb + (size_t)sn * 65536;
        const u16* gv = gvb + sn * 64;
        const uint4 kn0 = *(const uint4*)gk;
        const uint4 kn1 = *(const uint4*)(gk + 8);
        const uint4 vn0 = *(const uint4*)gv;
        const uint4 vn1 = *(const uint4*)(gv + 8);

        floatx4 accs[4];
        for (int ni = 0; ni < 4; ni++) accs[ni] = zero;
        #pragma unroll
        for (int ks = 0; ks < 2; ks++) {
            #pragma unroll
            for (int ni = 0; ni < 4; ni++) {
                const bf16x8 kf = *(const bf16x8*)&Ks[ks][ni * 16 + r16][quad * 8];
                accs[ni] = __builtin_amdgcn_mfma_f32_16x16x32_bf16(kf, qf[ks], accs[ni], 0, 0, 0);
            }
        }

        float mx = -INFINITY;
        #pragma unroll
        for (int ni = 0; ni < 4; ni++)
            #pragma unroll
            for (int r = 0; r < 4; r++) mx = fmaxf(mx, accs[ni][r]);
        mx = fmaxf(mx, __shfl_xor(mx, 16));
        mx = fmaxf(mx, __shfl_xor(mx, 32));
        const float mn = fmaxf(m_i, mx);
        const float al = exp2f((m_i - mn) * C1);
        m_i = mn;
        const float negmc = -mn * C1;
        float ps = 0.0f;
        #pragma unroll
        for (int ni = 0; ni < 4; ni++) {
            const float p0 = exp2f(fmaf(accs[ni][0], C1, negmc));
            const float p1 = exp2f(fmaf(accs[ni][1], C1, negmc));
            const float p2 = exp2f(fmaf(accs[ni][2], C1, negmc));
            const float p3 = exp2f(fmaf(accs[ni][3], C1, negmc));
            ps += (p0 + p1) + (p2 + p3);
            uint2 w;
            w.x = cvt_pk_bf16(p0, p1);
            w.y = cvt_pk_bf16(p2, p3);
            *(uint2*)&Ps[ni >> 1][wq + r16][(ni & 1) * 16 + quad * 4] = w;
        }
        ps += __shfl_xor(ps, 16);
        ps += __shfl_xor(ps, 32);
        l_i = l_i * al + ps;
        #pragma unroll
        for (int r = 0; r < 4; r++) {
            const float alr = __shfl(al, quad * 4 + r);
            #pragma unroll
            for (int ni = 0; ni < 4; ni++) acc_o[ni][r] *= alr;
        }

        #pragma unroll
        for (int ks = 0; ks < 2; ks++) {
            const bf16x8 af = *(const bf16x8*)&Ps[ks][wq + r16][quad * 8];
            #pragma unroll
            for (int ni = 0; ni < 4; ni++) {
                const bf16x8 bf = *(const bf16x8*)&Vs[ks][ni * 16 + r16][quad * 8];
                acc_o[ni] = __builtin_amdgcn_mfma_f32_16x16x32_bf16(af, bf, acc_o[ni], 0, 0, 0);
            }
        }

        k0v = kn0; k1v = kn1; v0v = vn0; v1v = vn1;
        __syncthreads();
    }

    for (int r = 0; r < 4; r++) {
        const float linv = 1.0f / __shfl(l_i, quad * 4 + r);
        const size_t rowoff = qk_base + (size_t)(q0 + wq + quad * 4 + r) * 1024;
        for (int ni = 0; ni < 4; ni++)
            ctx[rowoff + ni * 16 + r16] = f2b(acc_o[ni][r] * linv);
    }
}

// ---------------- launcher ----------------
extern "C" void kernel_launch(void* const* d_in, const int* in_sizes, int n_in,
                              void* d_out, int out_size, void* d_ws, size_t ws_size,
                              hipStream_t stream) {
    const float* x   = (const float*)d_in[0];
    const float* Wq  = (const float*)d_in[1];
    const float* bq  = (const float*)d_in[2];
    const float* Wk  = (const float*)d_in[3];
    const float* bk  = (const float*)d_in[4];
    const float* Wv  = (const float*)d_in[5];
    const float* bv  = (const float*)d_in[6];
    const float* Wo  = (const float*)d_in[7];
    const float* bo  = (const float*)d_in[8];
    const float* W1  = (const float*)d_in[9];
    const float* b1  = (const float*)d_in[10];
    const float* W2  = (const float*)d_in[11];
    const float* b2  = (const float*)d_in[12];
    const float* g1  = (const float*)d_in[13];
    const float* be1 = (const float*)d_in[14];
    const float* g2  = (const float*)d_in[15];
    const float* be2 = (const float*)d_in[16];
    float* out = (float*)d_out;

    const size_t MB = 1ull << 20;
    char* ws = (char*)d_ws;
    u16*   h_b    = (u16*)(ws + 0);            // 16MB bf16 h (residual for Wo)
    u16*   qkv_b  = (u16*)(ws + 16 * MB);      // 48MB: q|k|v each [8192][1024]
    u16*   q_b    = qkv_b;
    u16*   k_b    = (u16*)(ws + 32 * MB);
    u16*   v_b    = (u16*)(ws + 48 * MB);
    u16*   vt_b   = (u16*)(ws + 64 * MB);      // 16MB per-head transposed V
    u16*   ctx_b  = (u16*)(ws + 80 * MB);      // 16MB
    float* hres   = (float*)(ws + 96 * MB);    // 32MB fp32 (Wo out, LN2 in)
    u16*   h2_b   = (u16*)(ws + 128 * MB);     // 16MB
    u16*   g_b    = (u16*)(ws + 16 * MB);      // 64MB gelu acts (reuses qkv+vt)
    u16*   wqkv_t = (u16*)(ws + 160 * MB);     // 6MB [3072][1024]
    u16*   wo_t   = (u16*)(ws + 166 * MB);     // 2MB
    u16*   w1_t   = (u16*)(ws + 168 * MB);     // 8MB
    u16*   w2_t   = (u16*)(ws + 176 * MB);     // 8MB -> 184MB
    const int M = 8192, D = 1024, FF = 4096;
    const dim3 tb(32, 8);

    // weight prep
    k_tconv4<<<dim3(32, 32, 4), tb, 0, stream>>>(Wq, wqkv_t,
                                                 Wk, wqkv_t + 1024 * 1024,
                                                 Wv, wqkv_t + 2 * 1024 * 1024,
                                                 Wo, wo_t);
    k_tconv<<<dim3(128, 32), tb, 0, stream>>>(W1, w1_t, D, FF);
    k_tconv<<<dim3(32, 128), tb, 0, stream>>>(W2, w2_t, FF, D);

    // LN1 -> h_b (bf16)
    k_ln_bf<<<M, 256, 0, stream>>>(x, g1, be1, h_b);

    // fused QKV GEMM -> q|k|v (256² 8-phase)
    k_gemm256<false, true><<<dim3(12, 32), 512, 0, stream>>>(
        h_b, wqkv_t, bq, qkv_b, M, 3072, D, bk, bv);

    // per-head V transpose
    k_vtrans<<<dim3(16, 16, 8), 256, 0, stream>>>(v_b, vt_b);

    // MFMA flash attention -> ctx
    k_attn_mfma<<<2048, 256, 0, stream>>>(q_b, k_b, vt_b, ctx_b);

    // Wo + residual(h_b bf16) -> hres fp32
    k_gemm<false, true, true, false><<<dim3(8, 64), 256, 0, stream>>>(
        ctx_b, wo_t, bo, h_b, hres, nullptr, M, D, D);

    // LN2 -> h2_b (bf16)
    k_ln_bf<<<M, 256, 0, stream>>>(hres, g2, be2, h2_b);

    // FFN1 + exact GELU -> g_b (256² 8-phase)
    k_gemm256<true, false><<<dim3(16, 32), 512, 0, stream>>>(
        h2_b, w1_t, b1, g_b, M, FF, D);

    // FFN2 + residual(h2_b bf16) -> out fp32
    k_gemm<false, true, true, false><<<dim3(8, 64), 256, 0, stream>>>(
        g_b, w2_t, b2, h2_b, out, nullptr, M, D, FF);
}

// Round 5
// 900.664 us; speedup vs baseline: 1.0115x; 1.0115x over previous
//
#include <hip/hip_runtime.h>
#include <hip/hip_bf16.h>

// ---------------- common helpers ----------------
typedef unsigned short u16;
typedef __attribute__((ext_vector_type(8))) short bf16x8;
typedef __attribute__((ext_vector_type(4))) float floatx4;

__device__ __forceinline__ u16 f2b(float f) {
    union { float f; unsigned int u; } a; a.f = f;
    unsigned int u = a.u;
    unsigned int r = (u + 0x7fffu + ((u >> 16) & 1u)) >> 16; // RNE bf16
    return (u16)r;
}
__device__ __forceinline__ float b2f(u16 v) {
    union { unsigned int u; float f; } a; a.u = ((unsigned int)v) << 16;
    return a.f;
}
// pack two f32 -> one u32 of 2x bf16 (RNE), single instruction
__device__ __forceinline__ unsigned int cvt_pk_bf16(float lo, float hi) {
    unsigned int r;
    asm("v_cvt_pk_bf16_f32 %0, %1, %2" : "=v"(r) : "v"(lo), "v"(hi));
    return r;
}

// async global->LDS, 16B per lane (global_load_lds_dwordx4)
__device__ __forceinline__ void gload_lds16(const void* g, void* l) {
    auto gp = (const __attribute__((address_space(1))) unsigned int*)g;
    auto lp = (__attribute__((address_space(3))) unsigned int*)l;
    __builtin_amdgcn_global_load_lds(gp, lp, 16, 0, 0);
}

// pinned raw barrier (schedule may not cross)
__device__ __forceinline__ void sbar() {
    __builtin_amdgcn_sched_barrier(0);
    __builtin_amdgcn_s_barrier();
    __builtin_amdgcn_sched_barrier(0);
}

// ---------------- LayerNorm (ddof=1), bf16 out ----------------
__global__ __launch_bounds__(256) void k_ln_bf(const float* __restrict__ x,
                                               const float* __restrict__ g,
                                               const float* __restrict__ be,
                                               u16* __restrict__ yb) {
    const int row = blockIdx.x;
    const int t = threadIdx.x;
    const float4 xv = ((const float4*)(x + (size_t)row * 1024))[t];
    float s  = xv.x + xv.y + xv.z + xv.w;
    float ss = xv.x * xv.x + xv.y * xv.y + xv.z * xv.z + xv.w * xv.w;
    for (int m = 1; m < 64; m <<= 1) {
        s  += __shfl_xor(s, m);
        ss += __shfl_xor(ss, m);
    }
    __shared__ float sm[8];
    const int wave = t >> 6, lane = t & 63;
    if (lane == 0) { sm[wave] = s; sm[4 + wave] = ss; }
    __syncthreads();
    s  = sm[0] + sm[1] + sm[2] + sm[3];
    ss = sm[4] + sm[5] + sm[6] + sm[7];
    const float mean = s * (1.0f / 1024.0f);
    const float var  = (ss - 1024.0f * mean * mean) * (1.0f / 1023.0f); // ddof=1
    const float rstd = rsqrtf(var + 1e-5f);
    const float4 gv = ((const float4*)g)[t];
    const float4 bv = ((const float4*)be)[t];
    float4 y;
    y.x = (xv.x - mean) * rstd * gv.x + bv.x;
    y.y = (xv.y - mean) * rstd * gv.y + bv.y;
    y.z = (xv.z - mean) * rstd * gv.z + bv.z;
    y.w = (xv.w - mean) * rstd * gv.w + bv.w;
    uint2 pk;
    pk.x = (unsigned int)f2b(y.x) | ((unsigned int)f2b(y.y) << 16);
    pk.y = (unsigned int)f2b(y.z) | ((unsigned int)f2b(y.w) << 16);
    *(uint2*)(yb + (size_t)row * 1024 + t * 4) = pk;
}

// ---------------- weight transpose + convert: W(KxN) fp32 -> Wt(NxK) bf16 ----------------
__global__ __launch_bounds__(256) void k_tconv(const float* __restrict__ W,
                                               u16* __restrict__ Wt,
                                               int K, int N) {
    __shared__ float tile[32][33];
    const int n0 = blockIdx.x * 32, k0 = blockIdx.y * 32;
    const int tx = threadIdx.x, ty = threadIdx.y; // 32 x 8
    for (int i = 0; i < 4; i++) {
        const int kr = ty + i * 8;
        tile[kr][tx] = W[(size_t)(k0 + kr) * N + n0 + tx];
    }
    __syncthreads();
    for (int i = 0; i < 4; i++) {
        const int nr = ty + i * 8;
        Wt[(size_t)(n0 + nr) * K + k0 + tx] = f2b(tile[tx][nr]);
    }
}

// batched version for the four 1024x1024 weights (z selects)
__global__ __launch_bounds__(256) void k_tconv4(const float* __restrict__ s0, u16* __restrict__ d0,
                                                const float* __restrict__ s1, u16* __restrict__ d1,
                                                const float* __restrict__ s2, u16* __restrict__ d2,
                                                const float* __restrict__ s3, u16* __restrict__ d3) {
    __shared__ float tile[32][33];
    const float* W; u16* Wt;
    switch (blockIdx.z) {
        case 0: W = s0; Wt = d0; break;
        case 1: W = s1; Wt = d1; break;
        case 2: W = s2; Wt = d2; break;
        default: W = s3; Wt = d3; break;
    }
    const int n0 = blockIdx.x * 32, k0 = blockIdx.y * 32;
    const int tx = threadIdx.x, ty = threadIdx.y;
    for (int i = 0; i < 4; i++) {
        const int kr = ty + i * 8;
        tile[kr][tx] = W[(size_t)(k0 + kr) * 1024 + n0 + tx];
    }
    __syncthreads();
    for (int i = 0; i < 4; i++) {
        const int nr = ty + i * 8;
        Wt[(size_t)(n0 + nr) * 1024 + k0 + tx] = f2b(tile[tx][nr]);
    }
}

// ---------------- per-head V transpose: v[b*T][D] -> vt[b][h][d][t] (bf16) ----------------
__global__ __launch_bounds__(256) void k_vtrans(const u16* __restrict__ v,
                                                u16* __restrict__ vt) {
    __shared__ u16 tile[64][80];
    const int t = threadIdx.x;
    const int t0 = blockIdx.x * 64, hh = blockIdx.y, bb = blockIdx.z;
    const int r = t >> 2, c0 = (t & 3) * 16;
    const u16* src = v + ((size_t)(bb * 1024 + t0 + r)) * 1024 + hh * 64 + c0;
    *(uint4*)&tile[r][c0]     = *(const uint4*)src;
    *(uint4*)&tile[r][c0 + 8] = *(const uint4*)(src + 8);
    __syncthreads();
    const int d = t >> 2;
    u16* dst = vt + (((size_t)(bb * 16 + hh) * 64 + d)) * 1024 + t0 + c0;
    union { u16 s[8]; uint4 v4; } pk;
    for (int j = 0; j < 8; j++) pk.s[j] = tile[c0 + j][d];
    *(uint4*)dst = pk.v4;
    for (int j = 0; j < 8; j++) pk.s[j] = tile[c0 + 8 + j][d];
    *(uint4*)(dst + 8) = pk.v4;
}

// ---------------- 128x128 bf16 MFMA GEMM (kept for Wo / FFN2) ----------------
template <bool GELU, bool RESID, bool WF32, bool WBF16, bool QKV = false>
__global__ __launch_bounds__(256) void k_gemm(const u16* __restrict__ A,
                                              const u16* __restrict__ Bt,
                                              const float* __restrict__ bias,
                                              const u16* __restrict__ residB,
                                              float* __restrict__ outF,
                                              u16* __restrict__ outB,
                                              int M, int N, int K,
                                              const float* __restrict__ bias2 = nullptr,
                                              const float* __restrict__ bias3 = nullptr) {
    __shared__ __align__(16) u16 S[16896]; // As(8192) | Bs(8192); epilogue: 128x132 ctile
    u16* As = S;
    u16* Bs = S + 8192;
    const int t = threadIdx.x;

    // group-m swizzle
    const int nb = gridDim.x;
    const int linear = blockIdx.y * nb + blockIdx.x;
    const int per = nb * 8;
    const int gg = linear / per, rr = linear % per;
    const int m0 = (gg * 8 + (rr & 7)) * 128;
    const int n0 = (rr >> 3) * 128;

    const int lane = t & 63, wave = t >> 6;
    const int wm = (wave >> 1) * 64, wn = (wave & 1) * 64;
    const int r16 = lane & 15, quad = lane >> 4;

    floatx4 acc[4][4];
    const floatx4 zero = {0.0f, 0.0f, 0.0f, 0.0f};
    for (int i = 0; i < 4; i++)
        for (int j = 0; j < 4; j++) acc[i][j] = zero;

    const u16* pa[4];
    const u16* pb[4];
    #pragma unroll
    for (int i = 0; i < 4; i++) {
        const int L = t + i * 256;
        const int row = L >> 3, col = L & 7;
        const int gcol = col ^ (row & 7);
        pa[i] = A  + (size_t)(m0 + row) * K + gcol * 8;
        pb[i] = Bt + (size_t)(n0 + row) * K + gcol * 8;
    }

    for (int kk = 0; kk < K; kk += 64) {
        #pragma unroll
        for (int i = 0; i < 4; i++) {
            gload_lds16(pa[i] + kk, As + (t + i * 256) * 8);
            gload_lds16(pb[i] + kk, Bs + (t + i * 256) * 8);
        }
        __syncthreads();

        #pragma unroll
        for (int ks = 0; ks < 2; ks++) {
            bf16x8 af[4], bfr[4];
            #pragma unroll
            for (int i = 0; i < 4; i++) {
                const int ra = wm + i * 16 + r16;
                af[i] = *(const bf16x8*)(As + ra * 64 + (((ks << 2) + quad) ^ (ra & 7)) * 8);
                const int rb = wn + i * 16 + r16;
                bfr[i] = *(const bf16x8*)(Bs + rb * 64 + (((ks << 2) + quad) ^ (rb & 7)) * 8);
            }
            #pragma unroll
            for (int mi = 0; mi < 4; mi++)
                #pragma unroll
                for (int ni = 0; ni < 4; ni++)
                    acc[mi][ni] = __builtin_amdgcn_mfma_f32_16x16x32_bf16(af[mi], bfr[ni], acc[mi][ni], 0, 0, 0);
        }
        __syncthreads();
    }

    const int sect = QKV ? (n0 >> 10) : 0;
    const float* bp = QKV ? (sect == 0 ? bias : (sect == 1 ? bias2 : bias3)) : bias;
    u16* outQ = QKV ? (outB + (size_t)sect * (8192ull * 1024ull)) : outB;

    if (WBF16) {
        u16 (*ct)[132] = (u16(*)[132])S;
        for (int mi = 0; mi < 4; mi++)
            for (int ni = 0; ni < 4; ni++) {
                const int col = wn + ni * 16 + r16;
                const int coln = QKV ? ((n0 + col) & 1023) : (n0 + col);
                const float bv = bp[coln];
                for (int r = 0; r < 4; r++) {
                    const int row = wm + mi * 16 + quad * 4 + r;
                    float v = acc[mi][ni][r] + bv;
                    if (GELU) v = 0.5f * v * (1.0f + erff(v * 0.70710678118654752f));
                    ct[row][col] = f2b(v);
                }
            }
        __syncthreads();
        const int orow = t >> 1, oc = (t & 1) * 64;
        const int grow = m0 + orow;
        u16* dst = QKV ? (outQ + (size_t)grow * 1024 + ((n0 + oc) & 1023))
                       : (outB + (size_t)grow * N + n0 + oc);
        #pragma unroll
        for (int j = 0; j < 8; j++)
            *(uint4*)(dst + j * 8) = *(const uint4*)&ct[orow][oc + j * 8];
    } else {
        for (int mi = 0; mi < 4; mi++)
            for (int ni = 0; ni < 4; ni++) {
                const int gcol = n0 + wn + ni * 16 + r16;
                const float bv = bias[gcol];
                for (int r = 0; r < 4; r++) {
                    const int grow = m0 + wm + mi * 16 + quad * 4 + r;
                    float v = acc[mi][ni][r] + bv;
                    if (GELU) v = 0.5f * v * (1.0f + erff(v * 0.70710678118654752f));
                    const size_t o = (size_t)grow * N + gcol;
                    if (RESID) v += b2f(residB[o]);
                    if (WF32) outF[o] = v;
                }
            }
    }
}

// ---------------- 256x256 8-phase bf16 MFMA GEMM (T2+T3+T4+T5) ----------------
// 512 threads = 8 waves (2M x 4N), per-wave output 128x64, BK=64.
// Round-4 lesson: __launch_bounds__(512,2) only sets a FLOOR on waves/EU; the
// LLVM scheduler still targeted its default 4 waves/EU and spilled the whole
// 128-VGPR accumulator to scratch (VGPR_Count=128, ~490MB scratch traffic).
// Fix: amdgpu_waves_per_eu(2,2) pins min=max=2 -> 256-VGPR budget. 128KB LDS
// already limits to 1 block/CU = 2 waves/EU, so nothing is lost.
template <bool GELU, bool QKV>
__global__
__attribute__((amdgpu_flat_work_group_size(512, 512)))
__attribute__((amdgpu_waves_per_eu(2, 2)))
void k_gemm256(const u16* __restrict__ A,
               const u16* __restrict__ Bt,
               const float* __restrict__ bias,
               u16* __restrict__ outB,
               int M, int N, int K,
               const float* __restrict__ bias2 = nullptr,
               const float* __restrict__ bias3 = nullptr) {
    __shared__ __align__(16) u16 S[65536]; // 128 KB
    const int t = threadIdx.x;
    const int lane = t & 63, wave = t >> 6;
    const int wm = wave >> 2, wn = wave & 3;          // 2 x 4 wave grid
    const int r16 = lane & 15, quad = lane >> 4;

    // group-m swizzle (8 m-tiles per group span all n-tiles)
    const int nb = gridDim.x;
    const int linear = blockIdx.y * nb + blockIdx.x;
    const int per = nb * 8;
    const int gg = linear / per, rr = linear % per;
    const int m0 = (gg * 8 + (rr & 7)) * 256;
    const int n0 = (rr >> 3) * 256;

    floatx4 acc[8][4];
    const floatx4 zero = {0.0f, 0.0f, 0.0f, 0.0f};
    #pragma unroll
    for (int i = 0; i < 8; i++)
        #pragma unroll
        for (int j = 0; j < 4; j++) acc[i][j] = zero;

    // staging chunk offsets: chunk L=(row,col), source col pre-swizzled:
    // gcol = col ^ (row & 7). LDS[row][col] = G[row][col^(row&7)].
    int offA[4], offB[4];
    #pragma unroll
    for (int i = 0; i < 4; i++) {
        const int L = t + i * 512;
        const int row = L >> 3, col = L & 7;
        const int gcol = col ^ (row & 7);
        offA[i] = (m0 + row) * K + gcol * 8;
        offB[i] = (n0 + row) * K + gcol * 8;
    }

    auto stage = [&](int buf, int kk) {
        #pragma unroll
        for (int i = 0; i < 4; i++) {
            gload_lds16(A + offA[i] + kk, S + buf * 32768 + (t + i * 512) * 8);
            gload_lds16(Bt + offB[i] + kk, S + 16384 + buf * 32768 + (t + i * 512) * 8);
        }
    };

    const int NT = K >> 6;
    stage(0, 0);
    stage(1, 64);
    asm volatile("s_waitcnt vmcnt(8)" ::: "memory"); // buf0 ready, buf1 in flight
    sbar();

    for (int kt = 0; kt < NT; kt++) {
        const int cur = kt & 1;
        const u16* As = S + cur * 32768;
        const u16* Bs = S + 16384 + cur * 32768;

        bf16x8 av[2][4], bv[2][2];

        auto readA = [&](int half) {
            #pragma unroll
            for (int ks = 0; ks < 2; ks++)
                #pragma unroll
                for (int mi = 0; mi < 4; mi++) {
                    const int ra = wm * 128 + half + mi * 16 + r16;
                    av[ks][mi] = *(const bf16x8*)(As + ra * 64 + (((ks << 2) + quad) ^ (ra & 7)) * 8);
                }
        };
        auto readB = [&](int half) {
            #pragma unroll
            for (int ks = 0; ks < 2; ks++)
                #pragma unroll
                for (int ni = 0; ni < 2; ni++) {
                    const int rb = wn * 64 + half + ni * 16 + r16;
                    bv[ks][ni] = *(const bf16x8*)(Bs + rb * 64 + (((ks << 2) + quad) ^ (rb & 7)) * 8);
                }
        };
        auto quadmm = [&](int mo, int no) {
            __builtin_amdgcn_s_setprio(1);
            #pragma unroll
            for (int ks = 0; ks < 2; ks++)
                #pragma unroll
                for (int mi = 0; mi < 4; mi++)
                    #pragma unroll
                    for (int ni = 0; ni < 2; ni++)
                        acc[mo + mi][no + ni] = __builtin_amdgcn_mfma_f32_16x16x32_bf16(
                            av[ks][mi], bv[ks][ni], acc[mo + mi][no + ni], 0, 0, 0);
            __builtin_amdgcn_s_setprio(0);
        };

        // phase 0: Q00 — read a-lo, b-lo
        readA(0); readB(0);
        sbar();
        quadmm(0, 0);
        // phase 1: Q10 — read a-hi (b-lo still live)
        readA(64);
        sbar();
        quadmm(4, 0);
        // phase 2: Q11 — read b-hi (a-hi still live)
        readB(32);
        sbar();
        quadmm(4, 2);
        // phase 3: Q01 — re-read a-lo (b-hi still live)
        readA(0);
        sbar();
        quadmm(0, 2);

        // boundary: all reads of buf[cur] done -> restage it for kt+2
        sbar();
        if (kt + 2 < NT) {
            stage(cur, (kt + 2) << 6);
            asm volatile("s_waitcnt vmcnt(8)" ::: "memory"); // kt+1's 8 loads done
        } else if (kt + 1 < NT) {
            asm volatile("s_waitcnt vmcnt(0)" ::: "memory");
        }
        sbar();
    }

    // ---- epilogue: bias(+GELU) -> LDS repack -> coalesced 16B stores
    const int sect = QKV ? (n0 >> 10) : 0;
    const float* bp = QKV ? (sect == 0 ? bias : (sect == 1 ? bias2 : bias3)) : bias;
    u16* outQ = QKV ? (outB + (size_t)sect * (8192ull * 1024ull)) : outB;

    float bvv[4];
    #pragma unroll
    for (int ni = 0; ni < 4; ni++) {
        const int col = wn * 64 + ni * 16 + r16;
        bvv[ni] = bp[QKV ? ((n0 + col) & 1023) : (n0 + col)];
    }
    u16 (*ct)[260] = (u16(*)[260])S; // 128 x 260 u16 = 66.5 KB
    __syncthreads();
    for (int mh = 0; mh < 2; mh++) {
        if (wm == mh) {
            #pragma unroll
            for (int mi = 0; mi < 8; mi++)
                #pragma unroll
                for (int ni = 0; ni < 4; ni++) {
                    const int col = wn * 64 + ni * 16 + r16;
                    #pragma unroll
                    for (int r = 0; r < 4; r++) {
                        float v = acc[mi][ni][r] + bvv[ni];
                        if (GELU) v = 0.5f * v * (1.0f + erff(v * 0.70710678118654752f));
                        ct[mi * 16 + quad * 4 + r][col] = f2b(v);
                    }
                }
        }
        __syncthreads();
        const int orow = t >> 2, oc = (t & 3) * 64;
        const int grow = m0 + mh * 128 + orow;
        u16* dst = QKV ? (outQ + (size_t)grow * 1024 + ((n0 + oc) & 1023))
                       : (outB + (size_t)grow * N + n0 + oc);
        #pragma unroll
        for (int j = 0; j < 8; j++)
            *(uint4*)(dst + j * 8) = *(const uint4*)&ct[orow][oc + j * 8];
        __syncthreads();
    }
}

// ---------------- bf16 MFMA flash attention (v3, swapped QK^T softmax) ----------------
__global__ __launch_bounds__(256) void k_attn_mfma(const u16* __restrict__ q,
                                                   const u16* __restrict__ k,
                                                   const u16* __restrict__ vt,
                                                   u16* __restrict__ ctx) {
    __shared__ u16 Ks[2][64][40];
    __shared__ u16 Vs[2][64][40];
    __shared__ u16 Ps[2][64][40];
    const int t = threadIdx.x;
    const int lane = t & 63, wave = t >> 6;
    const int r16 = lane & 15, quad = lane >> 4;
    const int wq = wave * 16;
    const int bx = blockIdx.x;
    const int qt = bx & 15, hh = (bx >> 4) & 15, bb = bx >> 8;
    const size_t qk_base = ((size_t)bb * 1024) * 1024 + hh * 64;
    const size_t vt_base = ((size_t)(bb * 16 + hh) * 64) * 1024;
    const int q0 = qt * 64;
    const float C1 = 0.18033688011112042f; // 0.125 * log2(e)

    bf16x8 qf[2];
    {
        const u16* qp = q + qk_base + (size_t)(q0 + wq + r16) * 1024 + quad * 8;
        qf[0] = *(const bf16x8*)qp;
        qf[1] = *(const bf16x8*)(qp + 32);
    }

    const int srow = t >> 2, ch = t & 3;
    const int pnl = ch >> 1, soff = (ch & 1) * 16;
    const u16* gkb = k + qk_base + (size_t)srow * 1024 + ch * 16;
    const u16* gvb = vt + vt_base + (size_t)srow * 1024 + ch * 16;

    uint4 k0v = *(const uint4*)gkb;
    uint4 k1v = *(const uint4*)(gkb + 8);
    uint4 v0v = *(const uint4*)gvb;
    uint4 v1v = *(const uint4*)(gvb + 8);

    float m_i = -INFINITY, l_i = 0.0f;
    floatx4 acc_o[4];
    const floatx4 zero = {0.0f, 0.0f, 0.0f, 0.0f};
    for (int ni = 0; ni < 4; ni++) acc_o[ni] = zero;

    for (int st = 0; st < 16; st++) {
        *(uint4*)&Ks[pnl][srow][soff]     = k0v;
        *(uint4*)&Ks[pnl][srow][soff + 8] = k1v;
        *(uint4*)&Vs[pnl][srow][soff]     = v0v;
        *(uint4*)&Vs[pnl][srow][soff + 8] = v1v;
        __syncthreads();

        const int sn = (st + 1) & 15;
        const u16* gk = gkb + (size_t)sn * 65536;
        const u16* gv = gvb + sn * 64;
        const uint4 kn0 = *(const uint4*)gk;
        const uint4 kn1 = *(const uint4*)(gk + 8);
        const uint4 vn0 = *(const uint4*)gv;
        const uint4 vn1 = *(const uint4*)(gv + 8);

        floatx4 accs[4];
        for (int ni = 0; ni < 4; ni++) accs[ni] = zero;
        #pragma unroll
        for (int ks = 0; ks < 2; ks++) {
            #pragma unroll
            for (int ni = 0; ni < 4; ni++) {
                const bf16x8 kf = *(const bf16x8*)&Ks[ks][ni * 16 + r16][quad * 8];
                accs[ni] = __builtin_amdgcn_mfma_f32_16x16x32_bf16(kf, qf[ks], accs[ni], 0, 0, 0);
            }
        }

        float mx = -INFINITY;
        #pragma unroll
        for (int ni = 0; ni < 4; ni++)
            #pragma unroll
            for (int r = 0; r < 4; r++) mx = fmaxf(mx, accs[ni][r]);
        mx = fmaxf(mx, __shfl_xor(mx, 16));
        mx = fmaxf(mx, __shfl_xor(mx, 32));
        const float mn = fmaxf(m_i, mx);
        const float al = exp2f((m_i - mn) * C1);
        m_i = mn;
        const float negmc = -mn * C1;
        float ps = 0.0f;
        #pragma unroll
        for (int ni = 0; ni < 4; ni++) {
            const float p0 = exp2f(fmaf(accs[ni][0], C1, negmc));
            const float p1 = exp2f(fmaf(accs[ni][1], C1, negmc));
            const float p2 = exp2f(fmaf(accs[ni][2], C1, negmc));
            const float p3 = exp2f(fmaf(accs[ni][3], C1, negmc));
            ps += (p0 + p1) + (p2 + p3);
            uint2 w;
            w.x = cvt_pk_bf16(p0, p1);
            w.y = cvt_pk_bf16(p2, p3);
            *(uint2*)&Ps[ni >> 1][wq + r16][(ni & 1) * 16 + quad * 4] = w;
        }
        ps += __shfl_xor(ps, 16);
        ps += __shfl_xor(ps, 32);
        l_i = l_i * al + ps;
        #pragma unroll
        for (int r = 0; r < 4; r++) {
            const float alr = __shfl(al, quad * 4 + r);
            #pragma unroll
            for (int ni = 0; ni < 4; ni++) acc_o[ni][r] *= alr;
        }

        #pragma unroll
        for (int ks = 0; ks < 2; ks++) {
            const bf16x8 af = *(const bf16x8*)&Ps[ks][wq + r16][quad * 8];
            #pragma unroll
            for (int ni = 0; ni < 4; ni++) {
                const bf16x8 bf = *(const bf16x8*)&Vs[ks][ni * 16 + r16][quad * 8];
                acc_o[ni] = __builtin_amdgcn_mfma_f32_16x16x32_bf16(af, bf, acc_o[ni], 0, 0, 0);
            }
        }

        k0v = kn0; k1v = kn1; v0v = vn0; v1v = vn1;
        __syncthreads();
    }

    for (int r = 0; r < 4; r++) {
        const float linv = 1.0f / __shfl(l_i, quad * 4 + r);
        const size_t rowoff = qk_base + (size_t)(q0 + wq + quad * 4 + r) * 1024;
        for (int ni = 0; ni < 4; ni++)
            ctx[rowoff + ni * 16 + r16] = f2b(acc_o[ni][r] * linv);
    }
}

// ---------------- launcher ----------------
extern "C" void kernel_launch(void* const* d_in, const int* in_sizes, int n_in,
                              void* d_out, int out_size, void* d_ws, size_t ws_size,
                              hipStream_t stream) {
    const float* x   = (const float*)d_in[0];
    const float* Wq  = (const float*)d_in[1];
    const float* bq  = (const float*)d_in[2];
    const float* Wk  = (const float*)d_in[3];
    const float* bk  = (const float*)d_in[4];
    const float* Wv  = (const float*)d_in[5];
    const float* bv  = (const float*)d_in[6];
    const float* Wo  = (const float*)d_in[7];
    const float* bo  = (const float*)d_in[8];
    const float* W1  = (const float*)d_in[9];
    const float* b1  = (const float*)d_in[10];
    const float* W2  = (const float*)d_in[11];
    const float* b2  = (const float*)d_in[12];
    const float* g1  = (const float*)d_in[13];
    const float* be1 = (const float*)d_in[14];
    const float* g2  = (const float*)d_in[15];
    const float* be2 = (const float*)d_in[16];
    float* out = (float*)d_out;

    const size_t MB = 1ull << 20;
    char* ws = (char*)d_ws;
    u16*   h_b    = (u16*)(ws + 0);            // 16MB bf16 h (residual for Wo)
    u16*   qkv_b  = (u16*)(ws + 16 * MB);      // 48MB: q|k|v each [8192][1024]
    u16*   q_b    = qkv_b;
    u16*   k_b    = (u16*)(ws + 32 * MB);
    u16*   v_b    = (u16*)(ws + 48 * MB);
    u16*   vt_b   = (u16*)(ws + 64 * MB);      // 16MB per-head transposed V
    u16*   ctx_b  = (u16*)(ws + 80 * MB);      // 16MB
    float* hres   = (float*)(ws + 96 * MB);    // 32MB fp32 (Wo out, LN2 in)
    u16*   h2_b   = (u16*)(ws + 128 * MB);     // 16MB
    u16*   g_b    = (u16*)(ws + 16 * MB);      // 64MB gelu acts (reuses qkv+vt)
    u16*   wqkv_t = (u16*)(ws + 160 * MB);     // 6MB [3072][1024]
    u16*   wo_t   = (u16*)(ws + 166 * MB);     // 2MB
    u16*   w1_t   = (u16*)(ws + 168 * MB);     // 8MB
    u16*   w2_t   = (u16*)(ws + 176 * MB);     // 8MB -> 184MB
    const int M = 8192, D = 1024, FF = 4096;
    const dim3 tb(32, 8);

    // weight prep
    k_tconv4<<<dim3(32, 32, 4), tb, 0, stream>>>(Wq, wqkv_t,
                                                 Wk, wqkv_t + 1024 * 1024,
                                                 Wv, wqkv_t + 2 * 1024 * 1024,
                                                 Wo, wo_t);
    k_tconv<<<dim3(128, 32), tb, 0, stream>>>(W1, w1_t, D, FF);
    k_tconv<<<dim3(32, 128), tb, 0, stream>>>(W2, w2_t, FF, D);

    // LN1 -> h_b (bf16)
    k_ln_bf<<<M, 256, 0, stream>>>(x, g1, be1, h_b);

    // fused QKV GEMM -> q|k|v (256² 8-phase)
    k_gemm256<false, true><<<dim3(12, 32), 512, 0, stream>>>(
        h_b, wqkv_t, bq, qkv_b, M, 3072, D, bk, bv);

    // per-head V transpose
    k_vtrans<<<dim3(16, 16, 8), 256, 0, stream>>>(v_b, vt_b);

    // MFMA flash attention -> ctx
    k_attn_mfma<<<2048, 256, 0, stream>>>(q_b, k_b, vt_b, ctx_b);

    // Wo + residual(h_b bf16) -> hres fp32
    k_gemm<false, true, true, false><<<dim3(8, 64), 256, 0, stream>>>(
        ctx_b, wo_t, bo, h_b, hres, nullptr, M, D, D);

    // LN2 -> h2_b (bf16)
    k_ln_bf<<<M, 256, 0, stream>>>(hres, g2, be2, h2_b);

    // FFN1 + exact GELU -> g_b (256² 8-phase)
    k_gemm256<true, false><<<dim3(16, 32), 512, 0, stream>>>(
        h2_b, w1_t, b1, g_b, M, FF, D);

    // FFN2 + residual(h2_b bf16) -> out fp32
    k_gemm<false, true, true, false><<<dim3(8, 64), 256, 0, stream>>>(
        g_b, w2_t, b2, h2_b, out, nullptr, M, D, FF);
}

// Round 6
// 794.951 us; speedup vs baseline: 1.1460x; 1.1330x over previous
//
#include <hip/hip_runtime.h>
#include <hip/hip_bf16.h>

// ---------------- common helpers ----------------
typedef unsigned short u16;
typedef __attribute__((ext_vector_type(8))) short bf16x8;
typedef __attribute__((ext_vector_type(4))) float floatx4;

__device__ __forceinline__ u16 f2b(float f) {
    union { float f; unsigned int u; } a; a.f = f;
    unsigned int u = a.u;
    unsigned int r = (u + 0x7fffu + ((u >> 16) & 1u)) >> 16; // RNE bf16
    return (u16)r;
}
__device__ __forceinline__ float b2f(u16 v) {
    union { unsigned int u; float f; } a; a.u = ((unsigned int)v) << 16;
    return a.f;
}
// pack two f32 -> one u32 of 2x bf16 (RNE), single instruction
__device__ __forceinline__ unsigned int cvt_pk_bf16(float lo, float hi) {
    unsigned int r;
    asm("v_cvt_pk_bf16_f32 %0, %1, %2" : "=v"(r) : "v"(lo), "v"(hi));
    return r;
}

// async global->LDS, 16B per lane (global_load_lds_dwordx4)
__device__ __forceinline__ void gload_lds16(const void* g, void* l) {
    auto gp = (const __attribute__((address_space(1))) unsigned int*)g;
    auto lp = (__attribute__((address_space(3))) unsigned int*)l;
    __builtin_amdgcn_global_load_lds(gp, lp, 16, 0, 0);
}

// ---------------- LayerNorm (ddof=1), bf16 out ----------------
__global__ __launch_bounds__(256) void k_ln_bf(const float* __restrict__ x,
                                               const float* __restrict__ g,
                                               const float* __restrict__ be,
                                               u16* __restrict__ yb) {
    const int row = blockIdx.x;
    const int t = threadIdx.x;
    const float4 xv = ((const float4*)(x + (size_t)row * 1024))[t];
    float s  = xv.x + xv.y + xv.z + xv.w;
    float ss = xv.x * xv.x + xv.y * xv.y + xv.z * xv.z + xv.w * xv.w;
    for (int m = 1; m < 64; m <<= 1) {
        s  += __shfl_xor(s, m);
        ss += __shfl_xor(ss, m);
    }
    __shared__ float sm[8];
    const int wave = t >> 6, lane = t & 63;
    if (lane == 0) { sm[wave] = s; sm[4 + wave] = ss; }
    __syncthreads();
    s  = sm[0] + sm[1] + sm[2] + sm[3];
    ss = sm[4] + sm[5] + sm[6] + sm[7];
    const float mean = s * (1.0f / 1024.0f);
    const float var  = (ss - 1024.0f * mean * mean) * (1.0f / 1023.0f); // ddof=1
    const float rstd = rsqrtf(var + 1e-5f);
    const float4 gv = ((const float4*)g)[t];
    const float4 bv = ((const float4*)be)[t];
    float4 y;
    y.x = (xv.x - mean) * rstd * gv.x + bv.x;
    y.y = (xv.y - mean) * rstd * gv.y + bv.y;
    y.z = (xv.z - mean) * rstd * gv.z + bv.z;
    y.w = (xv.w - mean) * rstd * gv.w + bv.w;
    uint2 pk;
    pk.x = (unsigned int)f2b(y.x) | ((unsigned int)f2b(y.y) << 16);
    pk.y = (unsigned int)f2b(y.z) | ((unsigned int)f2b(y.w) << 16);
    *(uint2*)(yb + (size_t)row * 1024 + t * 4) = pk;
}

// ---------------- weight transpose + convert: W(KxN) fp32 -> Wt(NxK) bf16 ----------------
__global__ __launch_bounds__(256) void k_tconv(const float* __restrict__ W,
                                               u16* __restrict__ Wt,
                                               int K, int N) {
    __shared__ float tile[32][33];
    const int n0 = blockIdx.x * 32, k0 = blockIdx.y * 32;
    const int tx = threadIdx.x, ty = threadIdx.y; // 32 x 8
    for (int i = 0; i < 4; i++) {
        const int kr = ty + i * 8;
        tile[kr][tx] = W[(size_t)(k0 + kr) * N + n0 + tx];
    }
    __syncthreads();
    for (int i = 0; i < 4; i++) {
        const int nr = ty + i * 8;
        Wt[(size_t)(n0 + nr) * K + k0 + tx] = f2b(tile[tx][nr]);
    }
}

// batched version for the four 1024x1024 weights (z selects)
__global__ __launch_bounds__(256) void k_tconv4(const float* __restrict__ s0, u16* __restrict__ d0,
                                                const float* __restrict__ s1, u16* __restrict__ d1,
                                                const float* __restrict__ s2, u16* __restrict__ d2,
                                                const float* __restrict__ s3, u16* __restrict__ d3) {
    __shared__ float tile[32][33];
    const float* W; u16* Wt;
    switch (blockIdx.z) {
        case 0: W = s0; Wt = d0; break;
        case 1: W = s1; Wt = d1; break;
        case 2: W = s2; Wt = d2; break;
        default: W = s3; Wt = d3; break;
    }
    const int n0 = blockIdx.x * 32, k0 = blockIdx.y * 32;
    const int tx = threadIdx.x, ty = threadIdx.y;
    for (int i = 0; i < 4; i++) {
        const int kr = ty + i * 8;
        tile[kr][tx] = W[(size_t)(k0 + kr) * 1024 + n0 + tx];
    }
    __syncthreads();
    for (int i = 0; i < 4; i++) {
        const int nr = ty + i * 8;
        Wt[(size_t)(n0 + nr) * 1024 + k0 + tx] = f2b(tile[tx][nr]);
    }
}

// ---------------- per-head V transpose: v[b*T][D] -> vt[b][h][d][t] (bf16) ----------------
__global__ __launch_bounds__(256) void k_vtrans(const u16* __restrict__ v,
                                                u16* __restrict__ vt) {
    __shared__ u16 tile[64][80];
    const int t = threadIdx.x;
    const int t0 = blockIdx.x * 64, hh = blockIdx.y, bb = blockIdx.z;
    const int r = t >> 2, c0 = (t & 3) * 16;
    const u16* src = v + ((size_t)(bb * 1024 + t0 + r)) * 1024 + hh * 64 + c0;
    *(uint4*)&tile[r][c0]     = *(const uint4*)src;
    *(uint4*)&tile[r][c0 + 8] = *(const uint4*)(src + 8);
    __syncthreads();
    const int d = t >> 2;
    u16* dst = vt + (((size_t)(bb * 16 + hh) * 64 + d)) * 1024 + t0 + c0;
    union { u16 s[8]; uint4 v4; } pk;
    for (int j = 0; j < 8; j++) pk.s[j] = tile[c0 + j][d];
    *(uint4*)dst = pk.v4;
    for (int j = 0; j < 8; j++) pk.s[j] = tile[c0 + 8 + j][d];
    *(uint4*)(dst + 8) = pk.v4;
}

// ---------------- 128x128 bf16 MFMA GEMM (kept for Wo / FFN2) ----------------
template <bool GELU, bool RESID, bool WF32, bool WBF16, bool QKV = false>
__global__ __launch_bounds__(256) void k_gemm(const u16* __restrict__ A,
                                              const u16* __restrict__ Bt,
                                              const float* __restrict__ bias,
                                              const u16* __restrict__ residB,
                                              float* __restrict__ outF,
                                              u16* __restrict__ outB,
                                              int M, int N, int K,
                                              const float* __restrict__ bias2 = nullptr,
                                              const float* __restrict__ bias3 = nullptr) {
    __shared__ __align__(16) u16 S[16896]; // As(8192) | Bs(8192); epilogue: 128x132 ctile
    u16* As = S;
    u16* Bs = S + 8192;
    const int t = threadIdx.x;

    // group-m swizzle
    const int nb = gridDim.x;
    const int linear = blockIdx.y * nb + blockIdx.x;
    const int per = nb * 8;
    const int gg = linear / per, rr = linear % per;
    const int m0 = (gg * 8 + (rr & 7)) * 128;
    const int n0 = (rr >> 3) * 128;

    const int lane = t & 63, wave = t >> 6;
    const int wm = (wave >> 1) * 64, wn = (wave & 1) * 64;
    const int r16 = lane & 15, quad = lane >> 4;

    floatx4 acc[4][4];
    const floatx4 zero = {0.0f, 0.0f, 0.0f, 0.0f};
    for (int i = 0; i < 4; i++)
        for (int j = 0; j < 4; j++) acc[i][j] = zero;

    const u16* pa[4];
    const u16* pb[4];
    #pragma unroll
    for (int i = 0; i < 4; i++) {
        const int L = t + i * 256;
        const int row = L >> 3, col = L & 7;
        const int gcol = col ^ (row & 7);
        pa[i] = A  + (size_t)(m0 + row) * K + gcol * 8;
        pb[i] = Bt + (size_t)(n0 + row) * K + gcol * 8;
    }

    for (int kk = 0; kk < K; kk += 64) {
        #pragma unroll
        for (int i = 0; i < 4; i++) {
            gload_lds16(pa[i] + kk, As + (t + i * 256) * 8);
            gload_lds16(pb[i] + kk, Bs + (t + i * 256) * 8);
        }
        __syncthreads();

        #pragma unroll
        for (int ks = 0; ks < 2; ks++) {
            bf16x8 af[4], bfr[4];
            #pragma unroll
            for (int i = 0; i < 4; i++) {
                const int ra = wm + i * 16 + r16;
                af[i] = *(const bf16x8*)(As + ra * 64 + (((ks << 2) + quad) ^ (ra & 7)) * 8);
                const int rb = wn + i * 16 + r16;
                bfr[i] = *(const bf16x8*)(Bs + rb * 64 + (((ks << 2) + quad) ^ (rb & 7)) * 8);
            }
            #pragma unroll
            for (int mi = 0; mi < 4; mi++)
                #pragma unroll
                for (int ni = 0; ni < 4; ni++)
                    acc[mi][ni] = __builtin_amdgcn_mfma_f32_16x16x32_bf16(af[mi], bfr[ni], acc[mi][ni], 0, 0, 0);
        }
        __syncthreads();
    }

    const int sect = QKV ? (n0 >> 10) : 0;
    const float* bp = QKV ? (sect == 0 ? bias : (sect == 1 ? bias2 : bias3)) : bias;
    u16* outQ = QKV ? (outB + (size_t)sect * (8192ull * 1024ull)) : outB;

    if (WBF16) {
        u16 (*ct)[132] = (u16(*)[132])S;
        for (int mi = 0; mi < 4; mi++)
            for (int ni = 0; ni < 4; ni++) {
                const int col = wn + ni * 16 + r16;
                const int coln = QKV ? ((n0 + col) & 1023) : (n0 + col);
                const float bv = bp[coln];
                for (int r = 0; r < 4; r++) {
                    const int row = wm + mi * 16 + quad * 4 + r;
                    float v = acc[mi][ni][r] + bv;
                    if (GELU) v = 0.5f * v * (1.0f + erff(v * 0.70710678118654752f));
                    ct[row][col] = f2b(v);
                }
            }
        __syncthreads();
        const int orow = t >> 1, oc = (t & 1) * 64;
        const int grow = m0 + orow;
        u16* dst = QKV ? (outQ + (size_t)grow * 1024 + ((n0 + oc) & 1023))
                       : (outB + (size_t)grow * N + n0 + oc);
        #pragma unroll
        for (int j = 0; j < 8; j++)
            *(uint4*)(dst + j * 8) = *(const uint4*)&ct[orow][oc + j * 8];
    } else {
        for (int mi = 0; mi < 4; mi++)
            for (int ni = 0; ni < 4; ni++) {
                const int gcol = n0 + wn + ni * 16 + r16;
                const float bv = bias[gcol];
                for (int r = 0; r < 4; r++) {
                    const int grow = m0 + wm + mi * 16 + quad * 4 + r;
                    float v = acc[mi][ni][r] + bv;
                    if (GELU) v = 0.5f * v * (1.0f + erff(v * 0.70710678118654752f));
                    const size_t o = (size_t)grow * N + gcol;
                    if (RESID) v += b2f(residB[o]);
                    if (WF32) outF[o] = v;
                }
            }
    }
}

// ---------------- 256x256 bf16 MFMA GEMM, 16 waves x (64x64/wave) ----------------
// Round 3-5 lesson: the 8-wave/128x64-per-wave variant needs a 128-VGPR
// accumulator; LLVM pinned the budget at 128 and spilled it to scratch
// (~490MB/dispatch scratch traffic, MfmaUtil 6%), and neither
// __launch_bounds__(512,2) nor amdgpu_waves_per_eu(2,2) moved the allocator.
// This variant keeps the 256^2 tile but uses 16 waves (4x4) x 64x64 per wave:
// per-wave footprint IDENTICAL to the proven 128^2 kernel (acc 64 + frags 32
// + addr ~ 80 VGPR, no spill at the default 128 budget).
// Schedule (T3 minimal 2-phase): stage(next-buf) -> compute(cur) -> barrier.
// One barrier per K-tile; staging loads land under the 32-MFMA compute phase.
// LDS 128KB: [A0 16K | B0 16K | A1 16K | B1 16K] u16 units.
template <bool GELU, bool QKV>
__global__ __launch_bounds__(1024) void k_gemm256(const u16* __restrict__ A,
                                                  const u16* __restrict__ Bt,
                                                  const float* __restrict__ bias,
                                                  u16* __restrict__ outB,
                                                  int M, int N, int K,
                                                  const float* __restrict__ bias2 = nullptr,
                                                  const float* __restrict__ bias3 = nullptr) {
    __shared__ __align__(16) u16 S[65536]; // 128 KB
    const int t = threadIdx.x;
    const int lane = t & 63, wave = t >> 6;           // 16 waves
    const int wm = wave >> 2, wn = wave & 3;          // 4 x 4 wave grid
    const int r16 = lane & 15, quad = lane >> 4;

    // group-m swizzle (8 m-tiles per group span all n-tiles)
    const int nb = gridDim.x;
    const int linear = blockIdx.y * nb + blockIdx.x;
    const int per = nb * 8;
    const int gg = linear / per, rr = linear % per;
    const int m0 = (gg * 8 + (rr & 7)) * 256;
    const int n0 = (rr >> 3) * 256;

    floatx4 acc[4][4];
    const floatx4 zero = {0.0f, 0.0f, 0.0f, 0.0f};
    #pragma unroll
    for (int i = 0; i < 4; i++)
        #pragma unroll
        for (int j = 0; j < 4; j++) acc[i][j] = zero;

    // staging: per matrix 2048 chunks of 16B (256 rows x 8 chunks); 2 per thread.
    // source col pre-swizzled: LDS[row][col] = G[row][col ^ (row&7)].
    int offA[2], offB[2];
    #pragma unroll
    for (int i = 0; i < 2; i++) {
        const int L = t + i * 1024;
        const int row = L >> 3, col = L & 7;
        const int gcol = col ^ (row & 7);
        offA[i] = (m0 + row) * K + gcol * 8;
        offB[i] = (n0 + row) * K + gcol * 8;
    }

    const int NT = K >> 6;

    // prologue: stage tile 0 into buf0
    #pragma unroll
    for (int i = 0; i < 2; i++) {
        gload_lds16(A + offA[i], S + (t + i * 1024) * 8);
        gload_lds16(Bt + offB[i], S + 16384 + (t + i * 1024) * 8);
    }
    __syncthreads(); // drains vmcnt(0) before barrier

    for (int kt = 0; kt < NT; kt++) {
        const int cur = kt & 1;
        const u16* As = S + cur * 32768;
        const u16* Bs = S + 16384 + cur * 32768;

        // issue next tile's staging first (overlaps with compute below)
        if (kt + 1 < NT) {
            const int kk = (kt + 1) << 6;
            const int nxt = cur ^ 1;
            #pragma unroll
            for (int i = 0; i < 2; i++) {
                gload_lds16(A + offA[i] + kk, S + nxt * 32768 + (t + i * 1024) * 8);
                gload_lds16(Bt + offB[i] + kk, S + 16384 + nxt * 32768 + (t + i * 1024) * 8);
            }
        }

        // compute current tile: 2 ks-steps x {8 ds_read_b128, 16 MFMA}
        #pragma unroll
        for (int ks = 0; ks < 2; ks++) {
            bf16x8 af[4], bfr[4];
            #pragma unroll
            for (int i = 0; i < 4; i++) {
                const int ra = wm * 64 + i * 16 + r16;
                af[i] = *(const bf16x8*)(As + ra * 64 + (((ks << 2) + quad) ^ (ra & 7)) * 8);
                const int rb = wn * 64 + i * 16 + r16;
                bfr[i] = *(const bf16x8*)(Bs + rb * 64 + (((ks << 2) + quad) ^ (rb & 7)) * 8);
            }
            __builtin_amdgcn_s_setprio(1);
            #pragma unroll
            for (int mi = 0; mi < 4; mi++)
                #pragma unroll
                for (int ni = 0; ni < 4; ni++)
                    acc[mi][ni] = __builtin_amdgcn_mfma_f32_16x16x32_bf16(af[mi], bfr[ni], acc[mi][ni], 0, 0, 0);
            __builtin_amdgcn_s_setprio(0);
        }

        // one barrier per K-tile: drains staging loads (landed under compute)
        __syncthreads();
    }

    // ---- epilogue: bias(+GELU) -> LDS repack -> coalesced 16B stores
    const int sect = QKV ? (n0 >> 10) : 0;
    const float* bp = QKV ? (sect == 0 ? bias : (sect == 1 ? bias2 : bias3)) : bias;
    u16* outQ = QKV ? (outB + (size_t)sect * (8192ull * 1024ull)) : outB;

    float bvv[4];
    #pragma unroll
    for (int ni = 0; ni < 4; ni++) {
        const int col = wn * 64 + ni * 16 + r16;
        bvv[ni] = bp[QKV ? ((n0 + col) & 1023) : (n0 + col)];
    }
    u16 (*ct)[260] = (u16(*)[260])S; // 128 x 260 u16 = 65 KB
    for (int mh = 0; mh < 2; mh++) {
        if ((wm >> 1) == mh) {
            #pragma unroll
            for (int mi = 0; mi < 4; mi++)
                #pragma unroll
                for (int ni = 0; ni < 4; ni++) {
                    const int col = wn * 64 + ni * 16 + r16;
                    #pragma unroll
                    for (int r = 0; r < 4; r++) {
                        float v = acc[mi][ni][r] + bvv[ni];
                        if (GELU) v = 0.5f * v * (1.0f + erff(v * 0.70710678118654752f));
                        ct[(wm & 1) * 64 + mi * 16 + quad * 4 + r][col] = f2b(v);
                    }
                }
        }
        __syncthreads();
        const int orow = t >> 3, oc = (t & 7) * 32;
        const int grow = m0 + mh * 128 + orow;
        u16* dst = QKV ? (outQ + (size_t)grow * 1024 + ((n0 + oc) & 1023))
                       : (outB + (size_t)grow * N + n0 + oc);
        #pragma unroll
        for (int j = 0; j < 4; j++)
            *(uint4*)(dst + j * 8) = *(const uint4*)&ct[orow][oc + j * 8];
        __syncthreads();
    }
}

// ---------------- bf16 MFMA flash attention (v3, swapped QK^T softmax) ----------------
__global__ __launch_bounds__(256) void k_attn_mfma(const u16* __restrict__ q,
                                                   const u16* __restrict__ k,
                                                   const u16* __restrict__ vt,
                                                   u16* __restrict__ ctx) {
    __shared__ u16 Ks[2][64][40];
    __shared__ u16 Vs[2][64][40];
    __shared__ u16 Ps[2][64][40];
    const int t = threadIdx.x;
    const int lane = t & 63, wave = t >> 6;
    const int r16 = lane & 15, quad = lane >> 4;
    const int wq = wave * 16;
    const int bx = blockIdx.x;
    const int qt = bx & 15, hh = (bx >> 4) & 15, bb = bx >> 8;
    const size_t qk_base = ((size_t)bb * 1024) * 1024 + hh * 64;
    const size_t vt_base = ((size_t)(bb * 16 + hh) * 64) * 1024;
    const int q0 = qt * 64;
    const float C1 = 0.18033688011112042f; // 0.125 * log2(e)

    bf16x8 qf[2];
    {
        const u16* qp = q + qk_base + (size_t)(q0 + wq + r16) * 1024 + quad * 8;
        qf[0] = *(const bf16x8*)qp;
        qf[1] = *(const bf16x8*)(qp + 32);
    }

    const int srow = t >> 2, ch = t & 3;
    const int pnl = ch >> 1, soff = (ch & 1) * 16;
    const u16* gkb = k + qk_base + (size_t)srow * 1024 + ch * 16;
    const u16* gvb = vt + vt_base + (size_t)srow * 1024 + ch * 16;

    uint4 k0v = *(const uint4*)gkb;
    uint4 k1v = *(const uint4*)(gkb + 8);
    uint4 v0v = *(const uint4*)gvb;
    uint4 v1v = *(const uint4*)(gvb + 8);

    float m_i = -INFINITY, l_i = 0.0f;
    floatx4 acc_o[4];
    const floatx4 zero = {0.0f, 0.0f, 0.0f, 0.0f};
    for (int ni = 0; ni < 4; ni++) acc_o[ni] = zero;

    for (int st = 0; st < 16; st++) {
        *(uint4*)&Ks[pnl][srow][soff]     = k0v;
        *(uint4*)&Ks[pnl][srow][soff + 8] = k1v;
        *(uint4*)&Vs[pnl][srow][soff]     = v0v;
        *(uint4*)&Vs[pnl][srow][soff + 8] = v1v;
        __syncthreads();

        const int sn = (st + 1) & 15;
        const u16* gk = gkb + (size_t)sn * 65536;
        const u16* gv = gvb + sn * 64;
        const uint4 kn0 = *(const uint4*)gk;
        const uint4 kn1 = *(const uint4*)(gk + 8);
        const uint4 vn0 = *(const uint4*)gv;
        const uint4 vn1 = *(const uint4*)(gv + 8);

        floatx4 accs[4];
        for (int ni = 0; ni < 4; ni++) accs[ni] = zero;
        #pragma unroll
        for (int ks = 0; ks < 2; ks++) {
            #pragma unroll
            for (int ni = 0; ni < 4; ni++) {
                const bf16x8 kf = *(const bf16x8*)&Ks[ks][ni * 16 + r16][quad * 8];
                accs[ni] = __builtin_amdgcn_mfma_f32_16x16x32_bf16(kf, qf[ks], accs[ni], 0, 0, 0);
            }
        }

        float mx = -INFINITY;
        #pragma unroll
        for (int ni = 0; ni < 4; ni++)
            #pragma unroll
            for (int r = 0; r < 4; r++) mx = fmaxf(mx, accs[ni][r]);
        mx = fmaxf(mx, __shfl_xor(mx, 16));
        mx = fmaxf(mx, __shfl_xor(mx, 32));
        const float mn = fmaxf(m_i, mx);
        const float al = exp2f((m_i - mn) * C1);
        m_i = mn;
        const float negmc = -mn * C1;
        float ps = 0.0f;
        #pragma unroll
        for (int ni = 0; ni < 4; ni++) {
            const float p0 = exp2f(fmaf(accs[ni][0], C1, negmc));
            const float p1 = exp2f(fmaf(accs[ni][1], C1, negmc));
            const float p2 = exp2f(fmaf(accs[ni][2], C1, negmc));
            const float p3 = exp2f(fmaf(accs[ni][3], C1, negmc));
            ps += (p0 + p1) + (p2 + p3);
            uint2 w;
            w.x = cvt_pk_bf16(p0, p1);
            w.y = cvt_pk_bf16(p2, p3);
            *(uint2*)&Ps[ni >> 1][wq + r16][(ni & 1) * 16 + quad * 4] = w;
        }
        ps += __shfl_xor(ps, 16);
        ps += __shfl_xor(ps, 32);
        l_i = l_i * al + ps;
        #pragma unroll
        for (int r = 0; r < 4; r++) {
            const float alr = __shfl(al, quad * 4 + r);
            #pragma unroll
            for (int ni = 0; ni < 4; ni++) acc_o[ni][r] *= alr;
        }

        #pragma unroll
        for (int ks = 0; ks < 2; ks++) {
            const bf16x8 af = *(const bf16x8*)&Ps[ks][wq + r16][quad * 8];
            #pragma unroll
            for (int ni = 0; ni < 4; ni++) {
                const bf16x8 bf = *(const bf16x8*)&Vs[ks][ni * 16 + r16][quad * 8];
                acc_o[ni] = __builtin_amdgcn_mfma_f32_16x16x32_bf16(af, bf, acc_o[ni], 0, 0, 0);
            }
        }

        k0v = kn0; k1v = kn1; v0v = vn0; v1v = vn1;
        __syncthreads();
    }

    for (int r = 0; r < 4; r++) {
        const float linv = 1.0f / __shfl(l_i, quad * 4 + r);
        const size_t rowoff = qk_base + (size_t)(q0 + wq + quad * 4 + r) * 1024;
        for (int ni = 0; ni < 4; ni++)
            ctx[rowoff + ni * 16 + r16] = f2b(acc_o[ni][r] * linv);
    }
}

// ---------------- launcher ----------------
extern "C" void kernel_launch(void* const* d_in, const int* in_sizes, int n_in,
                              void* d_out, int out_size, void* d_ws, size_t ws_size,
                              hipStream_t stream) {
    const float* x   = (const float*)d_in[0];
    const float* Wq  = (const float*)d_in[1];
    const float* bq  = (const float*)d_in[2];
    const float* Wk  = (const float*)d_in[3];
    const float* bk  = (const float*)d_in[4];
    const float* Wv  = (const float*)d_in[5];
    const float* bv  = (const float*)d_in[6];
    const float* Wo  = (const float*)d_in[7];
    const float* bo  = (const float*)d_in[8];
    const float* W1  = (const float*)d_in[9];
    const float* b1  = (const float*)d_in[10];
    const float* W2  = (const float*)d_in[11];
    const float* b2  = (const float*)d_in[12];
    const float* g1  = (const float*)d_in[13];
    const float* be1 = (const float*)d_in[14];
    const float* g2  = (const float*)d_in[15];
    const float* be2 = (const float*)d_in[16];
    float* out = (float*)d_out;

    const size_t MB = 1ull << 20;
    char* ws = (char*)d_ws;
    u16*   h_b    = (u16*)(ws + 0);            // 16MB bf16 h (residual for Wo)
    u16*   qkv_b  = (u16*)(ws + 16 * MB);      // 48MB: q|k|v each [8192][1024]
    u16*   q_b    = qkv_b;
    u16*   k_b    = (u16*)(ws + 32 * MB);
    u16*   v_b    = (u16*)(ws + 48 * MB);
    u16*   vt_b   = (u16*)(ws + 64 * MB);      // 16MB per-head transposed V
    u16*   ctx_b  = (u16*)(ws + 80 * MB);      // 16MB
    float* hres   = (float*)(ws + 96 * MB);    // 32MB fp32 (Wo out, LN2 in)
    u16*   h2_b   = (u16*)(ws + 128 * MB);     // 16MB
    u16*   g_b    = (u16*)(ws + 16 * MB);      // 64MB gelu acts (reuses qkv+vt)
    u16*   wqkv_t = (u16*)(ws + 160 * MB);     // 6MB [3072][1024]
    u16*   wo_t   = (u16*)(ws + 166 * MB);     // 2MB
    u16*   w1_t   = (u16*)(ws + 168 * MB);     // 8MB
    u16*   w2_t   = (u16*)(ws + 176 * MB);     // 8MB -> 184MB
    const int M = 8192, D = 1024, FF = 4096;
    const dim3 tb(32, 8);

    // weight prep
    k_tconv4<<<dim3(32, 32, 4), tb, 0, stream>>>(Wq, wqkv_t,
                                                 Wk, wqkv_t + 1024 * 1024,
                                                 Wv, wqkv_t + 2 * 1024 * 1024,
                                                 Wo, wo_t);
    k_tconv<<<dim3(128, 32), tb, 0, stream>>>(W1, w1_t, D, FF);
    k_tconv<<<dim3(32, 128), tb, 0, stream>>>(W2, w2_t, FF, D);

    // LN1 -> h_b (bf16)
    k_ln_bf<<<M, 256, 0, stream>>>(x, g1, be1, h_b);

    // fused QKV GEMM -> q|k|v (256² 16-wave)
    k_gemm256<false, true><<<dim3(12, 32), 1024, 0, stream>>>(
        h_b, wqkv_t, bq, qkv_b, M, 3072, D, bk, bv);

    // per-head V transpose
    k_vtrans<<<dim3(16, 16, 8), 256, 0, stream>>>(v_b, vt_b);

    // MFMA flash attention -> ctx
    k_attn_mfma<<<2048, 256, 0, stream>>>(q_b, k_b, vt_b, ctx_b);

    // Wo + residual(h_b bf16) -> hres fp32
    k_gemm<false, true, true, false><<<dim3(8, 64), 256, 0, stream>>>(
        ctx_b, wo_t, bo, h_b, hres, nullptr, M, D, D);

    // LN2 -> h2_b (bf16)
    k_ln_bf<<<M, 256, 0, stream>>>(hres, g2, be2, h2_b);

    // FFN1 + exact GELU -> g_b (256² 16-wave)
    k_gemm256<true, false><<<dim3(16, 32), 1024, 0, stream>>>(
        h2_b, w1_t, b1, g_b, M, FF, D);

    // FFN2 + residual(h2_b bf16) -> out fp32
    k_gemm<false, true, true, false><<<dim3(8, 64), 256, 0, stream>>>(
        g_b, w2_t, b2, h2_b, out, nullptr, M, D, FF);
}

// Round 7
// 590.404 us; speedup vs baseline: 1.5430x; 1.3465x over previous
//
#include <hip/hip_runtime.h>
#include <hip/hip_bf16.h>

// ---------------- common helpers ----------------
typedef unsigned short u16;
typedef __attribute__((ext_vector_type(8))) short bf16x8;
typedef __attribute__((ext_vector_type(4))) float floatx4;

__device__ __forceinline__ u16 f2b(float f) {
    union { float f; unsigned int u; } a; a.f = f;
    unsigned int u = a.u;
    unsigned int r = (u + 0x7fffu + ((u >> 16) & 1u)) >> 16; // RNE bf16
    return (u16)r;
}
__device__ __forceinline__ float b2f(u16 v) {
    union { unsigned int u; float f; } a; a.u = ((unsigned int)v) << 16;
    return a.f;
}
// pack two f32 -> one u32 of 2x bf16 (RNE), single instruction
__device__ __forceinline__ unsigned int cvt_pk_bf16(float lo, float hi) {
    unsigned int r;
    asm("v_cvt_pk_bf16_f32 %0, %1, %2" : "=v"(r) : "v"(lo), "v"(hi));
    return r;
}

// async global->LDS, 16B per lane (global_load_lds_dwordx4)
__device__ __forceinline__ void gload_lds16(const void* g, void* l) {
    auto gp = (const __attribute__((address_space(1))) unsigned int*)g;
    auto lp = (__attribute__((address_space(3))) unsigned int*)l;
    __builtin_amdgcn_global_load_lds(gp, lp, 16, 0, 0);
}

// ---------------- LayerNorm (ddof=1), bf16 out ----------------
__global__ __launch_bounds__(256) void k_ln_bf(const float* __restrict__ x,
                                               const float* __restrict__ g,
                                               const float* __restrict__ be,
                                               u16* __restrict__ yb) {
    const int row = blockIdx.x;
    const int t = threadIdx.x;
    const float4 xv = ((const float4*)(x + (size_t)row * 1024))[t];
    float s  = xv.x + xv.y + xv.z + xv.w;
    float ss = xv.x * xv.x + xv.y * xv.y + xv.z * xv.z + xv.w * xv.w;
    for (int m = 1; m < 64; m <<= 1) {
        s  += __shfl_xor(s, m);
        ss += __shfl_xor(ss, m);
    }
    __shared__ float sm[8];
    const int wave = t >> 6, lane = t & 63;
    if (lane == 0) { sm[wave] = s; sm[4 + wave] = ss; }
    __syncthreads();
    s  = sm[0] + sm[1] + sm[2] + sm[3];
    ss = sm[4] + sm[5] + sm[6] + sm[7];
    const float mean = s * (1.0f / 1024.0f);
    const float var  = (ss - 1024.0f * mean * mean) * (1.0f / 1023.0f); // ddof=1
    const float rstd = rsqrtf(var + 1e-5f);
    const float4 gv = ((const float4*)g)[t];
    const float4 bv = ((const float4*)be)[t];
    float4 y;
    y.x = (xv.x - mean) * rstd * gv.x + bv.x;
    y.y = (xv.y - mean) * rstd * gv.y + bv.y;
    y.z = (xv.z - mean) * rstd * gv.z + bv.z;
    y.w = (xv.w - mean) * rstd * gv.w + bv.w;
    uint2 pk;
    pk.x = (unsigned int)f2b(y.x) | ((unsigned int)f2b(y.y) << 16);
    pk.y = (unsigned int)f2b(y.z) | ((unsigned int)f2b(y.w) << 16);
    *(uint2*)(yb + (size_t)row * 1024 + t * 4) = pk;
}

// ---------------- weight transpose + convert: W(KxN) fp32 -> Wt(NxK) bf16 ----------------
__global__ __launch_bounds__(256) void k_tconv(const float* __restrict__ W,
                                               u16* __restrict__ Wt,
                                               int K, int N) {
    __shared__ float tile[32][33];
    const int n0 = blockIdx.x * 32, k0 = blockIdx.y * 32;
    const int tx = threadIdx.x, ty = threadIdx.y; // 32 x 8
    for (int i = 0; i < 4; i++) {
        const int kr = ty + i * 8;
        tile[kr][tx] = W[(size_t)(k0 + kr) * N + n0 + tx];
    }
    __syncthreads();
    for (int i = 0; i < 4; i++) {
        const int nr = ty + i * 8;
        Wt[(size_t)(n0 + nr) * K + k0 + tx] = f2b(tile[tx][nr]);
    }
}

// batched version for the four 1024x1024 weights (z selects)
__global__ __launch_bounds__(256) void k_tconv4(const float* __restrict__ s0, u16* __restrict__ d0,
                                                const float* __restrict__ s1, u16* __restrict__ d1,
                                                const float* __restrict__ s2, u16* __restrict__ d2,
                                                const float* __restrict__ s3, u16* __restrict__ d3) {
    __shared__ float tile[32][33];
    const float* W; u16* Wt;
    switch (blockIdx.z) {
        case 0: W = s0; Wt = d0; break;
        case 1: W = s1; Wt = d1; break;
        case 2: W = s2; Wt = d2; break;
        default: W = s3; Wt = d3; break;
    }
    const int n0 = blockIdx.x * 32, k0 = blockIdx.y * 32;
    const int tx = threadIdx.x, ty = threadIdx.y;
    for (int i = 0; i < 4; i++) {
        const int kr = ty + i * 8;
        tile[kr][tx] = W[(size_t)(k0 + kr) * 1024 + n0 + tx];
    }
    __syncthreads();
    for (int i = 0; i < 4; i++) {
        const int nr = ty + i * 8;
        Wt[(size_t)(n0 + nr) * 1024 + k0 + tx] = f2b(tile[tx][nr]);
    }
}

// ---------------- per-head V transpose: v[b*T][D] -> vt[b][h][d][t] (bf16) ----------------
__global__ __launch_bounds__(256) void k_vtrans(const u16* __restrict__ v,
                                                u16* __restrict__ vt) {
    __shared__ u16 tile[64][80];
    const int t = threadIdx.x;
    const int t0 = blockIdx.x * 64, hh = blockIdx.y, bb = blockIdx.z;
    const int r = t >> 2, c0 = (t & 3) * 16;
    const u16* src = v + ((size_t)(bb * 1024 + t0 + r)) * 1024 + hh * 64 + c0;
    *(uint4*)&tile[r][c0]     = *(const uint4*)src;
    *(uint4*)&tile[r][c0 + 8] = *(const uint4*)(src + 8);
    __syncthreads();
    const int d = t >> 2;
    u16* dst = vt + (((size_t)(bb * 16 + hh) * 64 + d)) * 1024 + t0 + c0;
    union { u16 s[8]; uint4 v4; } pk;
    for (int j = 0; j < 8; j++) pk.s[j] = tile[c0 + j][d];
    *(uint4*)dst = pk.v4;
    for (int j = 0; j < 8; j++) pk.s[j] = tile[c0 + 8 + j][d];
    *(uint4*)(dst + 8) = pk.v4;
}

// ---------------- 128x128 bf16 MFMA GEMM (kept for Wo / FFN2) ----------------
template <bool GELU, bool RESID, bool WF32, bool WBF16, bool QKV = false>
__global__ __launch_bounds__(256) void k_gemm(const u16* __restrict__ A,
                                              const u16* __restrict__ Bt,
                                              const float* __restrict__ bias,
                                              const u16* __restrict__ residB,
                                              float* __restrict__ outF,
                                              u16* __restrict__ outB,
                                              int M, int N, int K,
                                              const float* __restrict__ bias2 = nullptr,
                                              const float* __restrict__ bias3 = nullptr) {
    __shared__ __align__(16) u16 S[16896]; // As(8192) | Bs(8192); epilogue: 128x132 ctile
    u16* As = S;
    u16* Bs = S + 8192;
    const int t = threadIdx.x;

    // group-m swizzle
    const int nb = gridDim.x;
    const int linear = blockIdx.y * nb + blockIdx.x;
    const int per = nb * 8;
    const int gg = linear / per, rr = linear % per;
    const int m0 = (gg * 8 + (rr & 7)) * 128;
    const int n0 = (rr >> 3) * 128;

    const int lane = t & 63, wave = t >> 6;
    const int wm = (wave >> 1) * 64, wn = (wave & 1) * 64;
    const int r16 = lane & 15, quad = lane >> 4;

    floatx4 acc[4][4];
    const floatx4 zero = {0.0f, 0.0f, 0.0f, 0.0f};
    for (int i = 0; i < 4; i++)
        for (int j = 0; j < 4; j++) acc[i][j] = zero;

    const u16* pa[4];
    const u16* pb[4];
    #pragma unroll
    for (int i = 0; i < 4; i++) {
        const int L = t + i * 256;
        const int row = L >> 3, col = L & 7;
        const int gcol = col ^ (row & 7);
        pa[i] = A  + (size_t)(m0 + row) * K + gcol * 8;
        pb[i] = Bt + (size_t)(n0 + row) * K + gcol * 8;
    }

    for (int kk = 0; kk < K; kk += 64) {
        #pragma unroll
        for (int i = 0; i < 4; i++) {
            gload_lds16(pa[i] + kk, As + (t + i * 256) * 8);
            gload_lds16(pb[i] + kk, Bs + (t + i * 256) * 8);
        }
        __syncthreads();

        #pragma unroll
        for (int ks = 0; ks < 2; ks++) {
            bf16x8 af[4], bfr[4];
            #pragma unroll
            for (int i = 0; i < 4; i++) {
                const int ra = wm + i * 16 + r16;
                af[i] = *(const bf16x8*)(As + ra * 64 + (((ks << 2) + quad) ^ (ra & 7)) * 8);
                const int rb = wn + i * 16 + r16;
                bfr[i] = *(const bf16x8*)(Bs + rb * 64 + (((ks << 2) + quad) ^ (rb & 7)) * 8);
            }
            #pragma unroll
            for (int mi = 0; mi < 4; mi++)
                #pragma unroll
                for (int ni = 0; ni < 4; ni++)
                    acc[mi][ni] = __builtin_amdgcn_mfma_f32_16x16x32_bf16(af[mi], bfr[ni], acc[mi][ni], 0, 0, 0);
        }
        __syncthreads();
    }

    const int sect = QKV ? (n0 >> 10) : 0;
    const float* bp = QKV ? (sect == 0 ? bias : (sect == 1 ? bias2 : bias3)) : bias;
    u16* outQ = QKV ? (outB + (size_t)sect * (8192ull * 1024ull)) : outB;

    if (WBF16) {
        u16 (*ct)[132] = (u16(*)[132])S;
        for (int mi = 0; mi < 4; mi++)
            for (int ni = 0; ni < 4; ni++) {
                const int col = wn + ni * 16 + r16;
                const int coln = QKV ? ((n0 + col) & 1023) : (n0 + col);
                const float bv = bp[coln];
                for (int r = 0; r < 4; r++) {
                    const int row = wm + mi * 16 + quad * 4 + r;
                    float v = acc[mi][ni][r] + bv;
                    if (GELU) v = 0.5f * v * (1.0f + erff(v * 0.70710678118654752f));
                    ct[row][col] = f2b(v);
                }
            }
        __syncthreads();
        const int orow = t >> 1, oc = (t & 1) * 64;
        const int grow = m0 + orow;
        u16* dst = QKV ? (outQ + (size_t)grow * 1024 + ((n0 + oc) & 1023))
                       : (outB + (size_t)grow * N + n0 + oc);
        #pragma unroll
        for (int j = 0; j < 8; j++)
            *(uint4*)(dst + j * 8) = *(const uint4*)&ct[orow][oc + j * 8];
    } else {
        for (int mi = 0; mi < 4; mi++)
            for (int ni = 0; ni < 4; ni++) {
                const int gcol = n0 + wn + ni * 16 + r16;
                const float bv = bias[gcol];
                for (int r = 0; r < 4; r++) {
                    const int grow = m0 + wm + mi * 16 + quad * 4 + r;
                    float v = acc[mi][ni][r] + bv;
                    if (GELU) v = 0.5f * v * (1.0f + erff(v * 0.70710678118654752f));
                    const size_t o = (size_t)grow * N + gcol;
                    if (RESID) v += b2f(residB[o]);
                    if (WF32) outF[o] = v;
                }
            }
    }
}

// ---------------- 256x128 bf16 MFMA GEMM, 8 waves x (64x64/wave) ----------------
// Round 3-6 lesson (VGPR-cap rule observed on this toolchain): allocator budget
// = pool / (2 x min-waves-from-block-size): 256thr->256, 512thr->128,
// 1024thr->64; LDS usage is ignored and no attribute overrides it. So the
// per-wave state must fit the cap. This shape: 512 threads (cap 128), 8 waves
// (4M x 2N) x 64x64 out per wave -> acc[4][4]=64 + af/bfr 32 + addr ~20 = ~115.
// Tile 256x128, BK=64, LDS 96KB double-buffered. 2-phase schedule: stage(next)
// -> compute(cur) -> one barrier per K-tile (T3 minimum; loads land under the
// 32-MFMA compute phase).
template <bool GELU, bool QKV>
__global__ __launch_bounds__(512) void k_gemm256(const u16* __restrict__ A,
                                                 const u16* __restrict__ Bt,
                                                 const float* __restrict__ bias,
                                                 u16* __restrict__ outB,
                                                 int M, int N, int K,
                                                 const float* __restrict__ bias2 = nullptr,
                                                 const float* __restrict__ bias3 = nullptr) {
    // layout (u16 units): As0[0,16384) As1[16384,32768) Bs0[32768,40960) Bs1[40960,49152)
    __shared__ __align__(16) u16 S[49152]; // 96 KB
    const int t = threadIdx.x;
    const int lane = t & 63, wave = t >> 6;           // 8 waves
    const int wm = wave >> 1, wn = wave & 1;          // 4 x 2 wave grid
    const int r16 = lane & 15, quad = lane >> 4;

    // group-m swizzle (8 m-tiles per group span all n-tiles); gridDim.y % 8 == 0
    const int nb = gridDim.x;
    const int linear = blockIdx.y * nb + blockIdx.x;
    const int per = nb * 8;
    const int gg = linear / per, rr = linear % per;
    const int m0 = (gg * 8 + (rr & 7)) * 256;
    const int n0 = (rr >> 3) * 128;

    floatx4 acc[4][4];
    const floatx4 zero = {0.0f, 0.0f, 0.0f, 0.0f};
    #pragma unroll
    for (int i = 0; i < 4; i++)
        #pragma unroll
        for (int j = 0; j < 4; j++) acc[i][j] = zero;

    // staging: A 256 rows x 8 chunks = 2048 chunks (4/thread); B 128 x 8 = 1024 (2/thread).
    // source col pre-swizzled: LDS[row][col] = G[row][col ^ (row&7)].
    int offA[4], offB[2];
    #pragma unroll
    for (int i = 0; i < 4; i++) {
        const int L = t + i * 512;
        const int row = L >> 3, col = L & 7;
        offA[i] = (m0 + row) * K + (col ^ (row & 7)) * 8;
    }
    #pragma unroll
    for (int i = 0; i < 2; i++) {
        const int L = t + i * 512;
        const int row = L >> 3, col = L & 7;
        offB[i] = (n0 + row) * K + (col ^ (row & 7)) * 8;
    }

    const int NT = K >> 6;

    // prologue: stage tile 0 into buf0
    #pragma unroll
    for (int i = 0; i < 4; i++)
        gload_lds16(A + offA[i], S + (t + i * 512) * 8);
    #pragma unroll
    for (int i = 0; i < 2; i++)
        gload_lds16(Bt + offB[i], S + 32768 + (t + i * 512) * 8);
    __syncthreads();

    for (int kt = 0; kt < NT; kt++) {
        const int cur = kt & 1;
        const u16* As = S + cur * 16384;
        const u16* Bs = S + 32768 + cur * 8192;

        // issue next tile's staging first (overlaps with compute below)
        if (kt + 1 < NT) {
            const int kk = (kt + 1) << 6;
            const int nxt = cur ^ 1;
            #pragma unroll
            for (int i = 0; i < 4; i++)
                gload_lds16(A + offA[i] + kk, S + nxt * 16384 + (t + i * 512) * 8);
            #pragma unroll
            for (int i = 0; i < 2; i++)
                gload_lds16(Bt + offB[i] + kk, S + 32768 + nxt * 8192 + (t + i * 512) * 8);
        }

        // compute current tile: 2 ks-steps x {8 ds_read_b128, 16 MFMA}
        #pragma unroll
        for (int ks = 0; ks < 2; ks++) {
            bf16x8 af[4], bfr[4];
            #pragma unroll
            for (int i = 0; i < 4; i++) {
                const int ra = wm * 64 + i * 16 + r16;
                af[i] = *(const bf16x8*)(As + ra * 64 + (((ks << 2) + quad) ^ (ra & 7)) * 8);
                const int rb = wn * 64 + i * 16 + r16;
                bfr[i] = *(const bf16x8*)(Bs + rb * 64 + (((ks << 2) + quad) ^ (rb & 7)) * 8);
            }
            __builtin_amdgcn_s_setprio(1);
            #pragma unroll
            for (int mi = 0; mi < 4; mi++)
                #pragma unroll
                for (int ni = 0; ni < 4; ni++)
                    acc[mi][ni] = __builtin_amdgcn_mfma_f32_16x16x32_bf16(af[mi], bfr[ni], acc[mi][ni], 0, 0, 0);
            __builtin_amdgcn_s_setprio(0);
        }

        // one barrier per K-tile: drains staging loads (landed under compute)
        __syncthreads();
    }

    // ---- epilogue: bias(+GELU) -> LDS repack (128-row halves) -> 16B stores
    const int sect = QKV ? (n0 >> 10) : 0;
    const float* bp = QKV ? (sect == 0 ? bias : (sect == 1 ? bias2 : bias3)) : bias;
    u16* outQ = QKV ? (outB + (size_t)sect * (8192ull * 1024ull)) : outB;

    float bvv[4];
    #pragma unroll
    for (int ni = 0; ni < 4; ni++) {
        const int col = wn * 64 + ni * 16 + r16;
        bvv[ni] = bp[QKV ? ((n0 + col) & 1023) : (n0 + col)];
    }
    u16 (*ct)[132] = (u16(*)[132])S; // 128 x 132 u16 = 33 KB (fits in S)
    for (int mh = 0; mh < 2; mh++) {
        if ((wm >> 1) == mh) {
            #pragma unroll
            for (int mi = 0; mi < 4; mi++)
                #pragma unroll
                for (int ni = 0; ni < 4; ni++) {
                    const int col = wn * 64 + ni * 16 + r16;
                    #pragma unroll
                    for (int r = 0; r < 4; r++) {
                        float v = acc[mi][ni][r] + bvv[ni];
                        if (GELU) v = 0.5f * v * (1.0f + erff(v * 0.70710678118654752f));
                        ct[(wm & 1) * 64 + mi * 16 + quad * 4 + r][col] = f2b(v);
                    }
                }
        }
        __syncthreads();
        const int orow = t >> 2, oc = (t & 3) * 32;
        const int grow = m0 + mh * 128 + orow;
        u16* dst = QKV ? (outQ + (size_t)grow * 1024 + ((n0 + oc) & 1023))
                       : (outB + (size_t)grow * N + n0 + oc);
        #pragma unroll
        for (int j = 0; j < 4; j++)
            *(uint4*)(dst + j * 8) = *(const uint4*)&ct[orow][oc + j * 8];
        __syncthreads();
    }
}

// ---------------- bf16 MFMA flash attention (v3, swapped QK^T softmax) ----------------
__global__ __launch_bounds__(256) void k_attn_mfma(const u16* __restrict__ q,
                                                   const u16* __restrict__ k,
                                                   const u16* __restrict__ vt,
                                                   u16* __restrict__ ctx) {
    __shared__ u16 Ks[2][64][40];
    __shared__ u16 Vs[2][64][40];
    __shared__ u16 Ps[2][64][40];
    const int t = threadIdx.x;
    const int lane = t & 63, wave = t >> 6;
    const int r16 = lane & 15, quad = lane >> 4;
    const int wq = wave * 16;
    const int bx = blockIdx.x;
    const int qt = bx & 15, hh = (bx >> 4) & 15, bb = bx >> 8;
    const size_t qk_base = ((size_t)bb * 1024) * 1024 + hh * 64;
    const size_t vt_base = ((size_t)(bb * 16 + hh) * 64) * 1024;
    const int q0 = qt * 64;
    const float C1 = 0.18033688011112042f; // 0.125 * log2(e)

    bf16x8 qf[2];
    {
        const u16* qp = q + qk_base + (size_t)(q0 + wq + r16) * 1024 + quad * 8;
        qf[0] = *(const bf16x8*)qp;
        qf[1] = *(const bf16x8*)(qp + 32);
    }

    const int srow = t >> 2, ch = t & 3;
    const int pnl = ch >> 1, soff = (ch & 1) * 16;
    const u16* gkb = k + qk_base + (size_t)srow * 1024 + ch * 16;
    const u16* gvb = vt + vt_base + (size_t)srow * 1024 + ch * 16;

    uint4 k0v = *(const uint4*)gkb;
    uint4 k1v = *(const uint4*)(gkb + 8);
    uint4 v0v = *(const uint4*)gvb;
    uint4 v1v = *(const uint4*)(gvb + 8);

    float m_i = -INFINITY, l_i = 0.0f;
    floatx4 acc_o[4];
    const floatx4 zero = {0.0f, 0.0f, 0.0f, 0.0f};
    for (int ni = 0; ni < 4; ni++) acc_o[ni] = zero;

    for (int st = 0; st < 16; st++) {
        *(uint4*)&Ks[pnl][srow][soff]     = k0v;
        *(uint4*)&Ks[pnl][srow][soff + 8] = k1v;
        *(uint4*)&Vs[pnl][srow][soff]     = v0v;
        *(uint4*)&Vs[pnl][srow][soff + 8] = v1v;
        __syncthreads();

        const int sn = (st + 1) & 15;
        const u16* gk = gkb + (size_t)sn * 65536;
        const u16* gv = gvb + sn * 64;
        const uint4 kn0 = *(const uint4*)gk;
        const uint4 kn1 = *(const uint4*)(gk + 8);
        const uint4 vn0 = *(const uint4*)gv;
        const uint4 vn1 = *(const uint4*)(gv + 8);

        floatx4 accs[4];
        for (int ni = 0; ni < 4; ni++) accs[ni] = zero;
        #pragma unroll
        for (int ks = 0; ks < 2; ks++) {
            #pragma unroll
            for (int ni = 0; ni < 4; ni++) {
                const bf16x8 kf = *(const bf16x8*)&Ks[ks][ni * 16 + r16][quad * 8];
                accs[ni] = __builtin_amdgcn_mfma_f32_16x16x32_bf16(kf, qf[ks], accs[ni], 0, 0, 0);
            }
        }

        float mx = -INFINITY;
        #pragma unroll
        for (int ni = 0; ni < 4; ni++)
            #pragma unroll
            for (int r = 0; r < 4; r++) mx = fmaxf(mx, accs[ni][r]);
        mx = fmaxf(mx, __shfl_xor(mx, 16));
        mx = fmaxf(mx, __shfl_xor(mx, 32));
        const float mn = fmaxf(m_i, mx);
        const float al = exp2f((m_i - mn) * C1);
        m_i = mn;
        const float negmc = -mn * C1;
        float ps = 0.0f;
        #pragma unroll
        for (int ni = 0; ni < 4; ni++) {
            const float p0 = exp2f(fmaf(accs[ni][0], C1, negmc));
            const float p1 = exp2f(fmaf(accs[ni][1], C1, negmc));
            const float p2 = exp2f(fmaf(accs[ni][2], C1, negmc));
            const float p3 = exp2f(fmaf(accs[ni][3], C1, negmc));
            ps += (p0 + p1) + (p2 + p3);
            uint2 w;
            w.x = cvt_pk_bf16(p0, p1);
            w.y = cvt_pk_bf16(p2, p3);
            *(uint2*)&Ps[ni >> 1][wq + r16][(ni & 1) * 16 + quad * 4] = w;
        }
        ps += __shfl_xor(ps, 16);
        ps += __shfl_xor(ps, 32);
        l_i = l_i * al + ps;
        #pragma unroll
        for (int r = 0; r < 4; r++) {
            const float alr = __shfl(al, quad * 4 + r);
            #pragma unroll
            for (int ni = 0; ni < 4; ni++) acc_o[ni][r] *= alr;
        }

        #pragma unroll
        for (int ks = 0; ks < 2; ks++) {
            const bf16x8 af = *(const bf16x8*)&Ps[ks][wq + r16][quad * 8];
            #pragma unroll
            for (int ni = 0; ni < 4; ni++) {
                const bf16x8 bf = *(const bf16x8*)&Vs[ks][ni * 16 + r16][quad * 8];
                acc_o[ni] = __builtin_amdgcn_mfma_f32_16x16x32_bf16(af, bf, acc_o[ni], 0, 0, 0);
            }
        }

        k0v = kn0; k1v = kn1; v0v = vn0; v1v = vn1;
        __syncthreads();
    }

    for (int r = 0; r < 4; r++) {
        const float linv = 1.0f / __shfl(l_i, quad * 4 + r);
        const size_t rowoff = qk_base + (size_t)(q0 + wq + quad * 4 + r) * 1024;
        for (int ni = 0; ni < 4; ni++)
            ctx[rowoff + ni * 16 + r16] = f2b(acc_o[ni][r] * linv);
    }
}

// ---------------- launcher ----------------
extern "C" void kernel_launch(void* const* d_in, const int* in_sizes, int n_in,
                              void* d_out, int out_size, void* d_ws, size_t ws_size,
                              hipStream_t stream) {
    const float* x   = (const float*)d_in[0];
    const float* Wq  = (const float*)d_in[1];
    const float* bq  = (const float*)d_in[2];
    const float* Wk  = (const float*)d_in[3];
    const float* bk  = (const float*)d_in[4];
    const float* Wv  = (const float*)d_in[5];
    const float* bv  = (const float*)d_in[6];
    const float* Wo  = (const float*)d_in[7];
    const float* bo  = (const float*)d_in[8];
    const float* W1  = (const float*)d_in[9];
    const float* b1  = (const float*)d_in[10];
    const float* W2  = (const float*)d_in[11];
    const float* b2  = (const float*)d_in[12];
    const float* g1  = (const float*)d_in[13];
    const float* be1 = (const float*)d_in[14];
    const float* g2  = (const float*)d_in[15];
    const float* be2 = (const float*)d_in[16];
    float* out = (float*)d_out;

    const size_t MB = 1ull << 20;
    char* ws = (char*)d_ws;
    u16*   h_b    = (u16*)(ws + 0);            // 16MB bf16 h (residual for Wo)
    u16*   qkv_b  = (u16*)(ws + 16 * MB);      // 48MB: q|k|v each [8192][1024]
    u16*   q_b    = qkv_b;
    u16*   k_b    = (u16*)(ws + 32 * MB);
    u16*   v_b    = (u16*)(ws + 48 * MB);
    u16*   vt_b   = (u16*)(ws + 64 * MB);      // 16MB per-head transposed V
    u16*   ctx_b  = (u16*)(ws + 80 * MB);      // 16MB
    float* hres   = (float*)(ws + 96 * MB);    // 32MB fp32 (Wo out, LN2 in)
    u16*   h2_b   = (u16*)(ws + 128 * MB);     // 16MB
    u16*   g_b    = (u16*)(ws + 16 * MB);      // 64MB gelu acts (reuses qkv+vt)
    u16*   wqkv_t = (u16*)(ws + 160 * MB);     // 6MB [3072][1024]
    u16*   wo_t   = (u16*)(ws + 166 * MB);     // 2MB
    u16*   w1_t   = (u16*)(ws + 168 * MB);     // 8MB
    u16*   w2_t   = (u16*)(ws + 176 * MB);     // 8MB -> 184MB
    const int M = 8192, D = 1024, FF = 4096;
    const dim3 tb(32, 8);

    // weight prep
    k_tconv4<<<dim3(32, 32, 4), tb, 0, stream>>>(Wq, wqkv_t,
                                                 Wk, wqkv_t + 1024 * 1024,
                                                 Wv, wqkv_t + 2 * 1024 * 1024,
                                                 Wo, wo_t);
    k_tconv<<<dim3(128, 32), tb, 0, stream>>>(W1, w1_t, D, FF);
    k_tconv<<<dim3(32, 128), tb, 0, stream>>>(W2, w2_t, FF, D);

    // LN1 -> h_b (bf16)
    k_ln_bf<<<M, 256, 0, stream>>>(x, g1, be1, h_b);

    // fused QKV GEMM -> q|k|v (256x128-tile, 8-wave)
    k_gemm256<false, true><<<dim3(24, 32), 512, 0, stream>>>(
        h_b, wqkv_t, bq, qkv_b, M, 3072, D, bk, bv);

    // per-head V transpose
    k_vtrans<<<dim3(16, 16, 8), 256, 0, stream>>>(v_b, vt_b);

    // MFMA flash attention -> ctx
    k_attn_mfma<<<2048, 256, 0, stream>>>(q_b, k_b, vt_b, ctx_b);

    // Wo + residual(h_b bf16) -> hres fp32
    k_gemm<false, true, true, false><<<dim3(8, 64), 256, 0, stream>>>(
        ctx_b, wo_t, bo, h_b, hres, nullptr, M, D, D);

    // LN2 -> h2_b (bf16)
    k_ln_bf<<<M, 256, 0, stream>>>(hres, g2, be2, h2_b);

    // FFN1 + exact GELU -> g_b (256x128-tile, 8-wave)
    k_gemm256<true, false><<<dim3(32, 32), 512, 0, stream>>>(
        h2_b, w1_t, b1, g_b, M, FF, D);

    // FFN2 + residual(h2_b bf16) -> out fp32
    k_gemm<false, true, true, false><<<dim3(8, 64), 256, 0, stream>>>(
        g_b, w2_t, b2, h2_b, out, nullptr, M, D, FF);
}

// Round 8
// 545.280 us; speedup vs baseline: 1.6707x; 1.0828x over previous
//
#include <hip/hip_runtime.h>
#include <hip/hip_bf16.h>

// ---------------- common helpers ----------------
typedef unsigned short u16;
typedef __attribute__((ext_vector_type(8))) short bf16x8;
typedef __attribute__((ext_vector_type(4))) float floatx4;

__device__ __forceinline__ u16 f2b(float f) {
    union { float f; unsigned int u; } a; a.f = f;
    unsigned int u = a.u;
    unsigned int r = (u + 0x7fffu + ((u >> 16) & 1u)) >> 16; // RNE bf16
    return (u16)r;
}
__device__ __forceinline__ float b2f(u16 v) {
    union { unsigned int u; float f; } a; a.u = ((unsigned int)v) << 16;
    return a.f;
}
// pack two f32 -> one u32 of 2x bf16 (RNE), single instruction
__device__ __forceinline__ unsigned int cvt_pk_bf16(float lo, float hi) {
    unsigned int r;
    asm("v_cvt_pk_bf16_f32 %0, %1, %2" : "=v"(r) : "v"(lo), "v"(hi));
    return r;
}

// async global->LDS, 16B per lane (global_load_lds_dwordx4)
__device__ __forceinline__ void gload_lds16(const void* g, void* l) {
    auto gp = (const __attribute__((address_space(1))) unsigned int*)g;
    auto lp = (__attribute__((address_space(3))) unsigned int*)l;
    __builtin_amdgcn_global_load_lds(gp, lp, 16, 0, 0);
}

// ---------------- LayerNorm (ddof=1), bf16 out ----------------
__global__ __launch_bounds__(256) void k_ln_bf(const float* __restrict__ x,
                                               const float* __restrict__ g,
                                               const float* __restrict__ be,
                                               u16* __restrict__ yb) {
    const int row = blockIdx.x;
    const int t = threadIdx.x;
    const float4 xv = ((const float4*)(x + (size_t)row * 1024))[t];
    float s  = xv.x + xv.y + xv.z + xv.w;
    float ss = xv.x * xv.x + xv.y * xv.y + xv.z * xv.z + xv.w * xv.w;
    for (int m = 1; m < 64; m <<= 1) {
        s  += __shfl_xor(s, m);
        ss += __shfl_xor(ss, m);
    }
    __shared__ float sm[8];
    const int wave = t >> 6, lane = t & 63;
    if (lane == 0) { sm[wave] = s; sm[4 + wave] = ss; }
    __syncthreads();
    s  = sm[0] + sm[1] + sm[2] + sm[3];
    ss = sm[4] + sm[5] + sm[6] + sm[7];
    const float mean = s * (1.0f / 1024.0f);
    const float var  = (ss - 1024.0f * mean * mean) * (1.0f / 1023.0f); // ddof=1
    const float rstd = rsqrtf(var + 1e-5f);
    const float4 gv = ((const float4*)g)[t];
    const float4 bv = ((const float4*)be)[t];
    float4 y;
    y.x = (xv.x - mean) * rstd * gv.x + bv.x;
    y.y = (xv.y - mean) * rstd * gv.y + bv.y;
    y.z = (xv.z - mean) * rstd * gv.z + bv.z;
    y.w = (xv.w - mean) * rstd * gv.w + bv.w;
    uint2 pk;
    pk.x = (unsigned int)f2b(y.x) | ((unsigned int)f2b(y.y) << 16);
    pk.y = (unsigned int)f2b(y.z) | ((unsigned int)f2b(y.w) << 16);
    *(uint2*)(yb + (size_t)row * 1024 + t * 4) = pk;
}

// ---------------- weight transpose + convert: W(KxN) fp32 -> Wt(NxK) bf16 ----------------
__global__ __launch_bounds__(256) void k_tconv(const float* __restrict__ W,
                                               u16* __restrict__ Wt,
                                               int K, int N) {
    __shared__ float tile[32][33];
    const int n0 = blockIdx.x * 32, k0 = blockIdx.y * 32;
    const int tx = threadIdx.x, ty = threadIdx.y; // 32 x 8
    for (int i = 0; i < 4; i++) {
        const int kr = ty + i * 8;
        tile[kr][tx] = W[(size_t)(k0 + kr) * N + n0 + tx];
    }
    __syncthreads();
    for (int i = 0; i < 4; i++) {
        const int nr = ty + i * 8;
        Wt[(size_t)(n0 + nr) * K + k0 + tx] = f2b(tile[tx][nr]);
    }
}

// batched version for the four 1024x1024 weights (z selects)
__global__ __launch_bounds__(256) void k_tconv4(const float* __restrict__ s0, u16* __restrict__ d0,
                                                const float* __restrict__ s1, u16* __restrict__ d1,
                                                const float* __restrict__ s2, u16* __restrict__ d2,
                                                const float* __restrict__ s3, u16* __restrict__ d3) {
    __shared__ float tile[32][33];
    const float* W; u16* Wt;
    switch (blockIdx.z) {
        case 0: W = s0; Wt = d0; break;
        case 1: W = s1; Wt = d1; break;
        case 2: W = s2; Wt = d2; break;
        default: W = s3; Wt = d3; break;
    }
    const int n0 = blockIdx.x * 32, k0 = blockIdx.y * 32;
    const int tx = threadIdx.x, ty = threadIdx.y;
    for (int i = 0; i < 4; i++) {
        const int kr = ty + i * 8;
        tile[kr][tx] = W[(size_t)(k0 + kr) * 1024 + n0 + tx];
    }
    __syncthreads();
    for (int i = 0; i < 4; i++) {
        const int nr = ty + i * 8;
        Wt[(size_t)(n0 + nr) * 1024 + k0 + tx] = f2b(tile[tx][nr]);
    }
}

// ---------------- per-head V transpose: v[b*T][D] -> vt[b][h][d][t] (bf16) ----------------
__global__ __launch_bounds__(256) void k_vtrans(const u16* __restrict__ v,
                                                u16* __restrict__ vt) {
    __shared__ u16 tile[64][80];
    const int t = threadIdx.x;
    const int t0 = blockIdx.x * 64, hh = blockIdx.y, bb = blockIdx.z;
    const int r = t >> 2, c0 = (t & 3) * 16;
    const u16* src = v + ((size_t)(bb * 1024 + t0 + r)) * 1024 + hh * 64 + c0;
    *(uint4*)&tile[r][c0]     = *(const uint4*)src;
    *(uint4*)&tile[r][c0 + 8] = *(const uint4*)(src + 8);
    __syncthreads();
    const int d = t >> 2;
    u16* dst = vt + (((size_t)(bb * 16 + hh) * 64 + d)) * 1024 + t0 + c0;
    union { u16 s[8]; uint4 v4; } pk;
    for (int j = 0; j < 8; j++) pk.s[j] = tile[c0 + j][d];
    *(uint4*)dst = pk.v4;
    for (int j = 0; j < 8; j++) pk.s[j] = tile[c0 + 8 + j][d];
    *(uint4*)(dst + 8) = pk.v4;
}

// ---------------- 128x128 bf16 MFMA GEMM (proven; all four GEMMs) ----------------
// Rounds 3-7 lesson: 256-thread blocks get a 256-VGPR budget (no spill at 80
// used); 512/1024-thread blocks are capped at 128/64 VGPR and every big-tile
// variant spilled its accumulator to scratch (up to 490MB/dispatch). The 128^2
// m97-structure kernel is the best spill-free configuration reachable here.
template <bool GELU, bool RESID, bool WF32, bool WBF16, bool QKV = false>
__global__ __launch_bounds__(256) void k_gemm(const u16* __restrict__ A,
                                              const u16* __restrict__ Bt,
                                              const float* __restrict__ bias,
                                              const u16* __restrict__ residB,
                                              float* __restrict__ outF,
                                              u16* __restrict__ outB,
                                              int M, int N, int K,
                                              const float* __restrict__ bias2 = nullptr,
                                              const float* __restrict__ bias3 = nullptr) {
    __shared__ __align__(16) u16 S[16896]; // As(8192) | Bs(8192); epilogue: 128x132 ctile
    u16* As = S;
    u16* Bs = S + 8192;
    const int t = threadIdx.x;

    // group-m swizzle
    const int nb = gridDim.x;
    const int linear = blockIdx.y * nb + blockIdx.x;
    const int per = nb * 8;
    const int gg = linear / per, rr = linear % per;
    const int m0 = (gg * 8 + (rr & 7)) * 128;
    const int n0 = (rr >> 3) * 128;

    const int lane = t & 63, wave = t >> 6;
    const int wm = (wave >> 1) * 64, wn = (wave & 1) * 64;
    const int r16 = lane & 15, quad = lane >> 4;

    floatx4 acc[4][4];
    const floatx4 zero = {0.0f, 0.0f, 0.0f, 0.0f};
    for (int i = 0; i < 4; i++)
        for (int j = 0; j < 4; j++) acc[i][j] = zero;

    const u16* pa[4];
    const u16* pb[4];
    #pragma unroll
    for (int i = 0; i < 4; i++) {
        const int L = t + i * 256;
        const int row = L >> 3, col = L & 7;
        const int gcol = col ^ (row & 7);
        pa[i] = A  + (size_t)(m0 + row) * K + gcol * 8;
        pb[i] = Bt + (size_t)(n0 + row) * K + gcol * 8;
    }

    for (int kk = 0; kk < K; kk += 64) {
        #pragma unroll
        for (int i = 0; i < 4; i++) {
            gload_lds16(pa[i] + kk, As + (t + i * 256) * 8);
            gload_lds16(pb[i] + kk, Bs + (t + i * 256) * 8);
        }
        __syncthreads();

        #pragma unroll
        for (int ks = 0; ks < 2; ks++) {
            bf16x8 af[4], bfr[4];
            #pragma unroll
            for (int i = 0; i < 4; i++) {
                const int ra = wm + i * 16 + r16;
                af[i] = *(const bf16x8*)(As + ra * 64 + (((ks << 2) + quad) ^ (ra & 7)) * 8);
                const int rb = wn + i * 16 + r16;
                bfr[i] = *(const bf16x8*)(Bs + rb * 64 + (((ks << 2) + quad) ^ (rb & 7)) * 8);
            }
            #pragma unroll
            for (int mi = 0; mi < 4; mi++)
                #pragma unroll
                for (int ni = 0; ni < 4; ni++)
                    acc[mi][ni] = __builtin_amdgcn_mfma_f32_16x16x32_bf16(af[mi], bfr[ni], acc[mi][ni], 0, 0, 0);
        }
        __syncthreads();
    }

    const int sect = QKV ? (n0 >> 10) : 0;
    const float* bp = QKV ? (sect == 0 ? bias : (sect == 1 ? bias2 : bias3)) : bias;
    u16* outQ = QKV ? (outB + (size_t)sect * (8192ull * 1024ull)) : outB;

    if (WBF16) {
        u16 (*ct)[132] = (u16(*)[132])S;
        for (int mi = 0; mi < 4; mi++)
            for (int ni = 0; ni < 4; ni++) {
                const int col = wn + ni * 16 + r16;
                const int coln = QKV ? ((n0 + col) & 1023) : (n0 + col);
                const float bv = bp[coln];
                for (int r = 0; r < 4; r++) {
                    const int row = wm + mi * 16 + quad * 4 + r;
                    float v = acc[mi][ni][r] + bv;
                    if (GELU) v = 0.5f * v * (1.0f + erff(v * 0.70710678118654752f));
                    ct[row][col] = f2b(v);
                }
            }
        __syncthreads();
        const int orow = t >> 1, oc = (t & 1) * 64;
        const int grow = m0 + orow;
        u16* dst = QKV ? (outQ + (size_t)grow * 1024 + ((n0 + oc) & 1023))
                       : (outB + (size_t)grow * N + n0 + oc);
        #pragma unroll
        for (int j = 0; j < 8; j++)
            *(uint4*)(dst + j * 8) = *(const uint4*)&ct[orow][oc + j * 8];
    } else {
        for (int mi = 0; mi < 4; mi++)
            for (int ni = 0; ni < 4; ni++) {
                const int gcol = n0 + wn + ni * 16 + r16;
                const float bv = bias[gcol];
                for (int r = 0; r < 4; r++) {
                    const int grow = m0 + wm + mi * 16 + quad * 4 + r;
                    float v = acc[mi][ni][r] + bv;
                    if (GELU) v = 0.5f * v * (1.0f + erff(v * 0.70710678118654752f));
                    const size_t o = (size_t)grow * N + gcol;
                    if (RESID) v += b2f(residB[o]);
                    if (WF32) outF[o] = v;
                }
            }
    }
}

// ---------------- bf16 MFMA flash attention (v4: v3 + XCD-affine block swizzle) ----------------
// grid 2048 blocks. Default dispatch round-robins consecutive blocks across the
// 8 XCDs, so the 16 q-tile blocks of one head (which share 256KB of K/V) land
// on 8 different L2s -> each XCD re-fetches the same KV (r1 counters: FETCH
// 147MB vs 48MB ideal). Bijective remap bx=(bid%8)*256+bid/8 gives each XCD
// 256 contiguous blocks = 16 whole heads = 4MB KV = exactly one XCD L2.
__global__ __launch_bounds__(256) void k_attn_mfma(const u16* __restrict__ q,
                                                   const u16* __restrict__ k,
                                                   const u16* __restrict__ vt,
                                                   u16* __restrict__ ctx) {
    __shared__ u16 Ks[2][64][40];
    __shared__ u16 Vs[2][64][40];
    __shared__ u16 Ps[2][64][40];
    const int t = threadIdx.x;
    const int lane = t & 63, wave = t >> 6;
    const int r16 = lane & 15, quad = lane >> 4;
    const int wq = wave * 16;
    const int bxr = blockIdx.x;
    const int bx = (bxr & 7) * 256 + (bxr >> 3); // XCD-affine (2048 % 8 == 0, bijective)
    const int qt = bx & 15, hh = (bx >> 4) & 15, bb = bx >> 8;
    const size_t qk_base = ((size_t)bb * 1024) * 1024 + hh * 64;
    const size_t vt_base = ((size_t)(bb * 16 + hh) * 64) * 1024;
    const int q0 = qt * 64;
    const float C1 = 0.18033688011112042f; // 0.125 * log2(e)

    bf16x8 qf[2];
    {
        const u16* qp = q + qk_base + (size_t)(q0 + wq + r16) * 1024 + quad * 8;
        qf[0] = *(const bf16x8*)qp;
        qf[1] = *(const bf16x8*)(qp + 32);
    }

    const int srow = t >> 2, ch = t & 3;
    const int pnl = ch >> 1, soff = (ch & 1) * 16;
    const u16* gkb = k + qk_base + (size_t)srow * 1024 + ch * 16;
    const u16* gvb = vt + vt_base + (size_t)srow * 1024 + ch * 16;

    uint4 k0v = *(const uint4*)gkb;
    uint4 k1v = *(const uint4*)(gkb + 8);
    uint4 v0v = *(const uint4*)gvb;
    uint4 v1v = *(const uint4*)(gvb + 8);

    float m_i = -INFINITY, l_i = 0.0f;
    floatx4 acc_o[4];
    const floatx4 zero = {0.0f, 0.0f, 0.0f, 0.0f};
    for (int ni = 0; ni < 4; ni++) acc_o[ni] = zero;

    for (int st = 0; st < 16; st++) {
        *(uint4*)&Ks[pnl][srow][soff]     = k0v;
        *(uint4*)&Ks[pnl][srow][soff + 8] = k1v;
        *(uint4*)&Vs[pnl][srow][soff]     = v0v;
        *(uint4*)&Vs[pnl][srow][soff + 8] = v1v;
        __syncthreads();

        const int sn = (st + 1) & 15;
        const u16* gk = gkb + (size_t)sn * 65536;
        const u16* gv = gvb + sn * 64;
        const uint4 kn0 = *(const uint4*)gk;
        const uint4 kn1 = *(const uint4*)(gk + 8);
        const uint4 vn0 = *(const uint4*)gv;
        const uint4 vn1 = *(const uint4*)(gv + 8);

        floatx4 accs[4];
        for (int ni = 0; ni < 4; ni++) accs[ni] = zero;
        #pragma unroll
        for (int ks = 0; ks < 2; ks++) {
            #pragma unroll
            for (int ni = 0; ni < 4; ni++) {
                const bf16x8 kf = *(const bf16x8*)&Ks[ks][ni * 16 + r16][quad * 8];
                accs[ni] = __builtin_amdgcn_mfma_f32_16x16x32_bf16(kf, qf[ks], accs[ni], 0, 0, 0);
            }
        }

        float mx = -INFINITY;
        #pragma unroll
        for (int ni = 0; ni < 4; ni++)
            #pragma unroll
            for (int r = 0; r < 4; r++) mx = fmaxf(mx, accs[ni][r]);
        mx = fmaxf(mx, __shfl_xor(mx, 16));
        mx = fmaxf(mx, __shfl_xor(mx, 32));
        const float mn = fmaxf(m_i, mx);
        const float al = exp2f((m_i - mn) * C1);
        m_i = mn;
        const float negmc = -mn * C1;
        float ps = 0.0f;
        #pragma unroll
        for (int ni = 0; ni < 4; ni++) {
            const float p0 = exp2f(fmaf(accs[ni][0], C1, negmc));
            const float p1 = exp2f(fmaf(accs[ni][1], C1, negmc));
            const float p2 = exp2f(fmaf(accs[ni][2], C1, negmc));
            const float p3 = exp2f(fmaf(accs[ni][3], C1, negmc));
            ps += (p0 + p1) + (p2 + p3);
            uint2 w;
            w.x = cvt_pk_bf16(p0, p1);
            w.y = cvt_pk_bf16(p2, p3);
            *(uint2*)&Ps[ni >> 1][wq + r16][(ni & 1) * 16 + quad * 4] = w;
        }
        ps += __shfl_xor(ps, 16);
        ps += __shfl_xor(ps, 32);
        l_i = l_i * al + ps;
        #pragma unroll
        for (int r = 0; r < 4; r++) {
            const float alr = __shfl(al, quad * 4 + r);
            #pragma unroll
            for (int ni = 0; ni < 4; ni++) acc_o[ni][r] *= alr;
        }

        #pragma unroll
        for (int ks = 0; ks < 2; ks++) {
            const bf16x8 af = *(const bf16x8*)&Ps[ks][wq + r16][quad * 8];
            #pragma unroll
            for (int ni = 0; ni < 4; ni++) {
                const bf16x8 bf = *(const bf16x8*)&Vs[ks][ni * 16 + r16][quad * 8];
                acc_o[ni] = __builtin_amdgcn_mfma_f32_16x16x32_bf16(af, bf, acc_o[ni], 0, 0, 0);
            }
        }

        k0v = kn0; k1v = kn1; v0v = vn0; v1v = vn1;
        __syncthreads();
    }

    for (int r = 0; r < 4; r++) {
        const float linv = 1.0f / __shfl(l_i, quad * 4 + r);
        const size_t rowoff = qk_base + (size_t)(q0 + wq + quad * 4 + r) * 1024;
        for (int ni = 0; ni < 4; ni++)
            ctx[rowoff + ni * 16 + r16] = f2b(acc_o[ni][r] * linv);
    }
}

// ---------------- launcher ----------------
extern "C" void kernel_launch(void* const* d_in, const int* in_sizes, int n_in,
                              void* d_out, int out_size, void* d_ws, size_t ws_size,
                              hipStream_t stream) {
    const float* x   = (const float*)d_in[0];
    const float* Wq  = (const float*)d_in[1];
    const float* bq  = (const float*)d_in[2];
    const float* Wk  = (const float*)d_in[3];
    const float* bk  = (const float*)d_in[4];
    const float* Wv  = (const float*)d_in[5];
    const float* bv  = (const float*)d_in[6];
    const float* Wo  = (const float*)d_in[7];
    const float* bo  = (const float*)d_in[8];
    const float* W1  = (const float*)d_in[9];
    const float* b1  = (const float*)d_in[10];
    const float* W2  = (const float*)d_in[11];
    const float* b2  = (const float*)d_in[12];
    const float* g1  = (const float*)d_in[13];
    const float* be1 = (const float*)d_in[14];
    const float* g2  = (const float*)d_in[15];
    const float* be2 = (const float*)d_in[16];
    float* out = (float*)d_out;

    const size_t MB = 1ull << 20;
    char* ws = (char*)d_ws;
    u16*   h_b    = (u16*)(ws + 0);            // 16MB bf16 h (residual for Wo)
    u16*   qkv_b  = (u16*)(ws + 16 * MB);      // 48MB: q|k|v each [8192][1024]
    u16*   q_b    = qkv_b;
    u16*   k_b    = (u16*)(ws + 32 * MB);
    u16*   v_b    = (u16*)(ws + 48 * MB);
    u16*   vt_b   = (u16*)(ws + 64 * MB);      // 16MB per-head transposed V
    u16*   ctx_b  = (u16*)(ws + 80 * MB);      // 16MB
    float* hres   = (float*)(ws + 96 * MB);    // 32MB fp32 (Wo out, LN2 in)
    u16*   h2_b   = (u16*)(ws + 128 * MB);     // 16MB
    u16*   g_b    = (u16*)(ws + 16 * MB);      // 64MB gelu acts (reuses qkv+vt)
    u16*   wqkv_t = (u16*)(ws + 160 * MB);     // 6MB [3072][1024]
    u16*   wo_t   = (u16*)(ws + 166 * MB);     // 2MB
    u16*   w1_t   = (u16*)(ws + 168 * MB);     // 8MB
    u16*   w2_t   = (u16*)(ws + 176 * MB);     // 8MB -> 184MB
    const int M = 8192, D = 1024, FF = 4096;
    const dim3 tb(32, 8);

    // weight prep
    k_tconv4<<<dim3(32, 32, 4), tb, 0, stream>>>(Wq, wqkv_t,
                                                 Wk, wqkv_t + 1024 * 1024,
                                                 Wv, wqkv_t + 2 * 1024 * 1024,
                                                 Wo, wo_t);
    k_tconv<<<dim3(128, 32), tb, 0, stream>>>(W1, w1_t, D, FF);
    k_tconv<<<dim3(32, 128), tb, 0, stream>>>(W2, w2_t, FF, D);

    // LN1 -> h_b (bf16)
    k_ln_bf<<<M, 256, 0, stream>>>(x, g1, be1, h_b);

    // fused QKV GEMM -> q|k|v (proven 128^2)
    k_gemm<false, false, false, true, true><<<dim3(24, 64), 256, 0, stream>>>(
        h_b, wqkv_t, bq, nullptr, nullptr, qkv_b, M, 3072, D, bk, bv);

    // per-head V transpose
    k_vtrans<<<dim3(16, 16, 8), 256, 0, stream>>>(v_b, vt_b);

    // MFMA flash attention -> ctx (v4: XCD-affine)
    k_attn_mfma<<<2048, 256, 0, stream>>>(q_b, k_b, vt_b, ctx_b);

    // Wo + residual(h_b bf16) -> hres fp32
    k_gemm<false, true, true, false><<<dim3(8, 64), 256, 0, stream>>>(
        ctx_b, wo_t, bo, h_b, hres, nullptr, M, D, D);

    // LN2 -> h2_b (bf16)
    k_ln_bf<<<M, 256, 0, stream>>>(hres, g2, be2, h2_b);

    // FFN1 + exact GELU -> g_b (proven 128^2)
    k_gemm<true, false, false, true><<<dim3(32, 64), 256, 0, stream>>>(
        h2_b, w1_t, b1, nullptr, nullptr, g_b, M, FF, D);

    // FFN2 + residual(h2_b bf16) -> out fp32
    k_gemm<false, true, true, false><<<dim3(8, 64), 256, 0, stream>>>(
        g_b, w2_t, b2, h2_b, out, nullptr, M, D, FF);
}